// Round 1
// 2044.008 us; speedup vs baseline: 1.1109x; 1.1109x over previous
//
#include <hip/hip_runtime.h>
#include <stdint.h>
#include <stddef.h>

// ---------- types ----------
typedef __bf16 bf16_8 __attribute__((ext_vector_type(8)));
typedef float  f32x4  __attribute__((ext_vector_type(4)));

__device__ __forceinline__ unsigned short f2bf(float f) {
    unsigned u = __float_as_uint(f);
    unsigned r = (u + 0x7fffu + ((u >> 16) & 1u)) >> 16;   // RTN-even
    return (unsigned short)r;
}
__device__ __forceinline__ float bf2f(unsigned short s) {
    return __uint_as_float(((unsigned)s) << 16);
}
__device__ __forceinline__ void split3(float v, unsigned short& h, unsigned short& l, unsigned short& l2) {
    h = f2bf(v);
    float r1 = v - bf2f(h);
    l = f2bf(r1);
    l2 = f2bf(r1 - bf2f(l));
}

// ---------- weight transpose+split: src [K][N] f32 -> dst planes [P][N][K] bf16 ----------
template<int P>
__global__ __launch_bounds__(256)
void wsplit_kernel(const float* __restrict__ s0, const float* __restrict__ s1,
                   const float* __restrict__ s2, const float* __restrict__ s3,
                   unsigned short* __restrict__ d0, unsigned short* __restrict__ d1,
                   unsigned short* __restrict__ d2, unsigned short* __restrict__ d3,
                   int K, int N, int nper, size_t sstride, size_t dstride)
{
    const int z = blockIdx.z;
    const int arr = z / nper, e = z - arr * nper;
    const float* src = (arr == 0 ? s0 : arr == 1 ? s1 : arr == 2 ? s2 : s3) + (size_t)e * sstride;
    unsigned short* dst = (arr == 0 ? d0 : arr == 1 ? d1 : arr == 2 ? d2 : d3) + (size_t)e * dstride;
    const size_t NK = (size_t)N * K;
    __shared__ float T[64][65];
    const int n0 = blockIdx.x * 64, k0 = blockIdx.y * 64;
    const int tid = threadIdx.x;
#pragma unroll
    for (int i = 0; i < 16; ++i) {
        int idx = tid + (i << 8);
        int kk = idx >> 6, nn = idx & 63;
        T[kk][nn] = src[(size_t)(k0 + kk) * N + n0 + nn];
    }
    __syncthreads();
#pragma unroll
    for (int i = 0; i < 4; ++i) {
        int idx = (tid + (i << 8)) << 2;
        int nn = idx >> 6, kk = idx & 63;
        ushort4 hv, lv, l2v;
        unsigned short* hp = (unsigned short*)&hv;
        unsigned short* lp = (unsigned short*)&lv;
        unsigned short* l2p = (unsigned short*)&l2v;
#pragma unroll
        for (int j = 0; j < 4; ++j) {
            float v = T[kk + j][nn];
            unsigned short h = f2bf(v);
            hp[j] = h;
            if (P == 3) {
                float r1 = v - bf2f(h);
                unsigned short l = f2bf(r1);
                lp[j] = l;
                l2p[j] = f2bf(r1 - bf2f(l));
            }
        }
        unsigned short* dp = dst + (size_t)(n0 + nn) * K + k0 + kk;
        *(ushort4*)dp = hv;
        if (P == 3) {
            *(ushort4*)(dp + NK) = lv;
            *(ushort4*)(dp + 2 * NK) = l2v;
        }
    }
}

// ---------- GEMM: C = A * B via bf16 MFMA, 128x128 tile, BK=32, expert-batched in z ----------
// TERMS=6: 3-term split both sides (fp32-grade). TERMS=1: plain bf16.
// AMODE: 0 direct (+e*astride); 1 compact base+row; 2 gather flat[base+row].
// CMODE: 0 direct (+e*cstride); 1 compact masked; 2 scatter flat[base+row] masked.
// BPRE: 0 = B f32 [K][N], in-loop split+transpose; 1 = B pre-split bf16 planes [P][N][K].
// A16:  0 = A f32, in-loop split; 1 = A bf16 [M][K], pure copy staging (TERMS must be 1).
// C16:  0 = C f32; 1 = C bf16.
template<int TERMS, int AMODE, int CMODE, int NW, int BPRE, int A16, int C16>
__global__ __launch_bounds__(256, 2)
void gemm_kernel(const void* __restrict__ Av,
                 const void* __restrict__ B0, const void* __restrict__ B1, const void* __restrict__ B2,
                 void* __restrict__ C0, void* __restrict__ C1, void* __restrict__ C2,
                 int M, int N, int K,
                 size_t astride, size_t bstride, size_t cstride,
                 const int* __restrict__ OFF, const int* __restrict__ flat)
{
    const int z = blockIdx.z;
    const int e = z / NW, w = z - e * NW;
    int base = 0, cnt = M;
    if (AMODE == 1 || AMODE == 2 || CMODE == 1 || CMODE == 2) {
        base = OFF[e * 8];
        cnt  = OFF[e * 8 + 8] - base;
        if ((int)blockIdx.x * 128 >= cnt) return;
    }
    const void* Bsel = (NW == 3 ? (w == 0 ? B0 : w == 1 ? B1 : B2) : B0);
    void*       Csel = (NW == 3 ? (w == 0 ? C0 : w == 1 ? C1 : C2) : C0);
    const float*          Af = (const float*)Av + (size_t)e * astride;
    const unsigned short* As = (const unsigned short*)Av;
    const float*          Bf = (const float*)Bsel + (size_t)e * bstride;
    const unsigned short* Bp = (const unsigned short*)Bsel + (size_t)e * bstride;
    float*          Cf = (float*)Csel + (size_t)e * cstride;
    unsigned short* Cs = (unsigned short*)Csel + (size_t)e * cstride;
    const size_t NKb = (size_t)N * K;

    constexpr int NPL = (TERMS == 6) ? 3 : 1;
    __shared__ unsigned short Asm[NPL][128 * 40];   // padded stride 40
    __shared__ unsigned short Bsm[NPL][128 * 40];   // Bsm[n][k]

    const int tid   = threadIdx.x;
    const int lane  = tid & 63;
    const int wid   = tid >> 6;
    const int wm    = wid & 1, wn = wid >> 1;
    const int mlane = lane & 15, quad = lane >> 4;
    const int row0  = blockIdx.x * 128;
    const int col0  = blockIdx.y * 128;

    f32x4 acc[4][4];
#pragma unroll
    for (int i = 0; i < 4; ++i)
#pragma unroll
        for (int j = 0; j < 4; ++j)
#pragma unroll
            for (int r = 0; r < 4; ++r) acc[i][j][r] = 0.f;

    for (int k0 = 0; k0 < K; k0 += 32) {
        // ---- stage A ----
        if (A16 == 0) {
#pragma unroll
            for (int i = 0; i < 4; ++i) {
                int idx = tid + (i << 8);
                int r = idx >> 3;
                int c = (idx & 7) << 2;
                int lr = row0 + r;
                if (AMODE != 0) lr = min(lr, cnt - 1);
                size_t arow = (AMODE == 2) ? (size_t)flat[base + lr]
                            : (AMODE == 1) ? (size_t)(base + lr) : (size_t)lr;
                const float4 a = *(const float4*)(Af + arow * K + k0 + c);
                float av[4] = {a.x, a.y, a.z, a.w};
                ushort4 hv, lv, l2v;
                unsigned short* hp  = (unsigned short*)&hv;
                unsigned short* lp  = (unsigned short*)&lv;
                unsigned short* l2p = (unsigned short*)&l2v;
#pragma unroll
                for (int j = 0; j < 4; ++j) {
                    unsigned short h = f2bf(av[j]);
                    hp[j] = h;
                    if (TERMS == 6) {
                        float r1 = av[j] - bf2f(h);
                        unsigned short l = f2bf(r1);
                        lp[j]  = l;
                        l2p[j] = f2bf(r1 - bf2f(l));
                    }
                }
                *(ushort4*)&Asm[0][r * 40 + c] = hv;
                if (TERMS == 6) {
                    *(ushort4*)&Asm[1][r * 40 + c] = lv;
                    *(ushort4*)&Asm[2][r * 40 + c] = l2v;
                }
            }
        } else {
#pragma unroll
            for (int j = 0; j < 2; ++j) {
                int c = tid * 2 + j;                 // 512 chunks of 8 shorts
                int r = c >> 2, q8 = (c & 3) << 3;
                int lr = row0 + r;
                if (AMODE != 0) lr = min(lr, cnt - 1);
                size_t arow = (AMODE == 2) ? (size_t)flat[base + lr]
                            : (AMODE == 1) ? (size_t)(base + lr) : (size_t)lr;
                *(uint4*)&Asm[0][r * 40 + q8] = *(const uint4*)(As + arow * K + k0 + q8);
            }
        }
        // ---- stage B ----
        if (BPRE == 0) {
#pragma unroll
            for (int i = 0; i < 2; ++i) {
                int idx = tid + (i << 8);
                int kk = idx >> 4;
                int n8 = (idx & 15) << 3;
                const float* bp = Bf + (size_t)(k0 + kk) * N + col0 + n8;
                const float4 b0 = *(const float4*)bp;
                const float4 b1 = *(const float4*)(bp + 4);
                float bv[8] = {b0.x, b0.y, b0.z, b0.w, b1.x, b1.y, b1.z, b1.w};
#pragma unroll
                for (int j = 0; j < 8; ++j) {
                    unsigned short h = f2bf(bv[j]);
                    Bsm[0][(n8 + j) * 40 + kk] = h;
                    if (TERMS == 6) {
                        float r1 = bv[j] - bf2f(h);
                        unsigned short l = f2bf(r1);
                        Bsm[1][(n8 + j) * 40 + kk] = l;
                        Bsm[2][(n8 + j) * 40 + kk] = f2bf(r1 - bf2f(l));
                    }
                }
            }
        } else {
#pragma unroll
            for (int p = 0; p < NPL; ++p)
#pragma unroll
                for (int j = 0; j < 2; ++j) {
                    int c = tid * 2 + j;
                    int r = c >> 2, q8 = (c & 3) << 3;
                    *(uint4*)&Bsm[p][r * 40 + q8] =
                        *(const uint4*)(Bp + (size_t)p * NKb + (size_t)(col0 + r) * K + k0 + q8);
                }
        }
        __syncthreads();

        bf16_8 fa[3][4], fb[3][4];
#pragma unroll
        for (int t = 0; t < 4; ++t) {
            int ar = (wm * 64 + t * 16 + mlane) * 40 + quad * 8;
            int br = (wn * 64 + t * 16 + mlane) * 40 + quad * 8;
            fa[0][t] = *(const bf16_8*)&Asm[0][ar];
            fb[0][t] = *(const bf16_8*)&Bsm[0][br];
            if (TERMS == 6) {
                fa[1][t] = *(const bf16_8*)&Asm[1][ar];
                fa[2][t] = *(const bf16_8*)&Asm[2][ar];
                fb[1][t] = *(const bf16_8*)&Bsm[1][br];
                fb[2][t] = *(const bf16_8*)&Bsm[2][br];
            }
        }
        const int ta[6] = {0, 0, 1, 0, 1, 2};
        const int tb[6] = {0, 1, 0, 2, 1, 0};
#pragma unroll
        for (int s = 0; s < TERMS; ++s)
#pragma unroll
            for (int mt = 0; mt < 4; ++mt)
#pragma unroll
                for (int nt = 0; nt < 4; ++nt)
                    acc[mt][nt] = __builtin_amdgcn_mfma_f32_16x16x32_bf16(
                        fa[ta[s]][mt], fb[tb[s]][nt], acc[mt][nt], 0, 0, 0);
        __syncthreads();
    }

    // ---- epilogue: C/D layout col=lane&15, row=quad*4+reg ----
#pragma unroll
    for (int mt = 0; mt < 4; ++mt)
#pragma unroll
        for (int nt = 0; nt < 4; ++nt) {
            int c = col0 + wn * 64 + nt * 16 + mlane;
#pragma unroll
            for (int j = 0; j < 4; ++j) {
                int lr = row0 + wm * 64 + mt * 16 + quad * 4 + j;
                if ((CMODE == 1 || CMODE == 2) && lr >= cnt) continue;
                size_t crow = (CMODE == 2) ? (size_t)flat[base + lr]
                            : (CMODE == 1) ? (size_t)(base + lr) : (size_t)lr;
                if (C16) Cs[crow * N + c] = f2bf(acc[mt][nt][j]);
                else     Cf[crow * N + c] = acc[mt][nt][j];
            }
        }
}

// ---------- MFMA split-bf16 flash attention (shared block), fp32-grade ----------
// 64 q per block (16 q per wave), KVBLK=32. Swapped operands:
//   S^T[key][q] = K·Q^T  (6-term, 3-plane split)  -> lane-local softmax per q-row
//   O^T[d][q]   = V^T·P^T (6-term, 3-plane split of P and V)
// LDS 60KB -> 2 blocks/CU. Replaces the fp32-VALU version that sat at the
// LDS-BW roofline (64x read amplification, 32GB LDS traffic = 464us floor).
__global__ __launch_bounds__(256, 2)
void attn_kernel(const float* __restrict__ Q, const float* __restrict__ Km,
                 const float* __restrict__ V, float* __restrict__ O)
{
    __shared__ __align__(16) unsigned short Ks[3][2][32][40];  // [plane][dchunk][key][dmod32+pad]
    __shared__ __align__(16) unsigned short Vt[3][64][40];     // [plane][d][key+pad]
    __shared__ __align__(16) unsigned short U[15360];          // Qs [3][2][64][40] / P [4][3][16][40]

    const int tid = threadIdx.x;
    const int lane = tid & 63;
    const int w = tid >> 6;
    const int mlane = lane & 15, quad = lane >> 4;

    const int qt = blockIdx.x & 15;
    const int h  = (blockIdx.x >> 4) & 7;
    const int b  = blockIdx.x >> 7;
    const size_t rowbase = (size_t)b * 1024;
    const int colbase = h * 64;

    // ---- stage Q tile (64 q x 64 d) as 3 bf16 planes ----
#pragma unroll
    for (int i = 0; i < 4; ++i) {
        int idx = tid + (i << 8);
        int r = idx >> 4, c4 = (idx & 15) << 2;
        const float4 a = *(const float4*)(Q + (rowbase + qt * 64 + r) * 512 + colbase + c4);
        float av[4] = {a.x, a.y, a.z, a.w};
        ushort4 hv, lv, l2v;
        unsigned short* hp  = (unsigned short*)&hv;
        unsigned short* lp  = (unsigned short*)&lv;
        unsigned short* l2p = (unsigned short*)&l2v;
#pragma unroll
        for (int j = 0; j < 4; ++j) split3(av[j], hp[j], lp[j], l2p[j]);
        int ch = c4 >> 5, cm = c4 & 31;
        *(ushort4*)&U[(((0 * 2 + ch) * 64) + r) * 40 + cm] = hv;
        *(ushort4*)&U[(((1 * 2 + ch) * 64) + r) * 40 + cm] = lv;
        *(ushort4*)&U[(((2 * 2 + ch) * 64) + r) * 40 + cm] = l2v;
    }
    __syncthreads();

    // Q B-fragments: col=q=w*16+mlane, k=d=c*32+quad*8+j  (persist in regs)
    bf16_8 fq[3][2];
#pragma unroll
    for (int p = 0; p < 3; ++p)
#pragma unroll
        for (int c = 0; c < 2; ++c)
            fq[p][c] = *(const bf16_8*)&U[(((p * 2 + c) * 64) + (w * 16 + mlane)) * 40 + quad * 8];
    __syncthreads();   // all waves done reading Qs before P region reuses U

    f32x4 oacc[4];     // O^T frags: d = mm*16+quad*4+j, q = mlane
#pragma unroll
    for (int i = 0; i < 4; ++i)
#pragma unroll
        for (int j = 0; j < 4; ++j) oacc[i][j] = 0.f;
    float m_run = -1e30f, l_run = 0.f;

    const int ta[6] = {0, 0, 1, 0, 1, 2};
    const int tb[6] = {0, 1, 0, 2, 1, 0};

    for (int tt = 0; tt < 32; ++tt) {
        __syncthreads();
        // ---- stage K tile (32 keys x 64 d), natural layout ----
#pragma unroll
        for (int i = 0; i < 2; ++i) {
            int idx = tid + (i << 8);
            int r = idx >> 4, c4 = (idx & 15) << 2;
            const float4 a = *(const float4*)(Km + (rowbase + tt * 32 + r) * 512 + colbase + c4);
            float av[4] = {a.x, a.y, a.z, a.w};
            ushort4 hv, lv, l2v;
            unsigned short* hp  = (unsigned short*)&hv;
            unsigned short* lp  = (unsigned short*)&lv;
            unsigned short* l2p = (unsigned short*)&l2v;
#pragma unroll
            for (int j = 0; j < 4; ++j) split3(av[j], hp[j], lp[j], l2p[j]);
            int ch = c4 >> 5, cm = c4 & 31;
            *(ushort4*)&Ks[0][ch][r][cm] = hv;
            *(ushort4*)&Ks[1][ch][r][cm] = lv;
            *(ushort4*)&Ks[2][ch][r][cm] = l2v;
        }
        // ---- stage V tile transposed: Vt[d][key] (coalesced dword loads) ----
#pragma unroll
        for (int i = 0; i < 2; ++i) {
            int idx = tid + (i << 8);
            int d = idx & 63, k4 = (idx >> 6) << 2;
            const float* vp = V + (rowbase + tt * 32 + k4) * 512 + colbase + d;
            float vv[4] = {vp[0], vp[512], vp[1024], vp[1536]};
            ushort4 hv, lv, l2v;
            unsigned short* hp  = (unsigned short*)&hv;
            unsigned short* lp  = (unsigned short*)&lv;
            unsigned short* l2p = (unsigned short*)&l2v;
#pragma unroll
            for (int j = 0; j < 4; ++j) split3(vv[j], hp[j], lp[j], l2p[j]);
            *(ushort4*)&Vt[0][d][k4] = hv;
            *(ushort4*)&Vt[1][d][k4] = lv;
            *(ushort4*)&Vt[2][d][k4] = l2v;
        }
        __syncthreads();

        // ---- S^T = K·Q^T, 6-term ----
        f32x4 sacc[2];
#pragma unroll
        for (int mm = 0; mm < 2; ++mm)
#pragma unroll
            for (int j = 0; j < 4; ++j) sacc[mm][j] = 0.f;
        bf16_8 fk[3][2][2];
#pragma unroll
        for (int p = 0; p < 3; ++p)
#pragma unroll
            for (int c = 0; c < 2; ++c)
#pragma unroll
                for (int mm = 0; mm < 2; ++mm)
                    fk[p][c][mm] = *(const bf16_8*)&Ks[p][c][mm * 16 + mlane][quad * 8];
#pragma unroll
        for (int s = 0; s < 6; ++s)
#pragma unroll
            for (int c = 0; c < 2; ++c)
#pragma unroll
                for (int mm = 0; mm < 2; ++mm)
                    sacc[mm] = __builtin_amdgcn_mfma_f32_16x16x32_bf16(
                        fk[ta[s]][c][mm], fq[tb[s]][c], sacc[mm], 0, 0, 0);

        // ---- online softmax: lane owns q=mlane, keys mm*16+quad*4+j ----
        float sv[2][4];
#pragma unroll
        for (int mm = 0; mm < 2; ++mm)
#pragma unroll
            for (int j = 0; j < 4; ++j) sv[mm][j] = sacc[mm][j] * 0.125f;
        float tmax = sv[0][0];
#pragma unroll
        for (int mm = 0; mm < 2; ++mm)
#pragma unroll
            for (int j = 0; j < 4; ++j) tmax = fmaxf(tmax, sv[mm][j]);
        tmax = fmaxf(tmax, __shfl_xor(tmax, 16));
        tmax = fmaxf(tmax, __shfl_xor(tmax, 32));
        float mnew = fmaxf(m_run, tmax);
        float alpha = __expf(m_run - mnew);
        float lsum = 0.f;
#pragma unroll
        for (int mm = 0; mm < 2; ++mm)
#pragma unroll
            for (int j = 0; j < 4; ++j) {
                float p = __expf(sv[mm][j] - mnew);
                sv[mm][j] = p;
                lsum += p;
            }
        lsum += __shfl_xor(lsum, 16);
        lsum += __shfl_xor(lsum, 32);
        l_run = l_run * alpha + lsum;
        m_run = mnew;
#pragma unroll
        for (int mm = 0; mm < 4; ++mm)
#pragma unroll
            for (int j = 0; j < 4; ++j) oacc[mm][j] *= alpha;

        // ---- split P to 3 bf16 planes, per-wave LDS round-trip ----
#pragma unroll
        for (int mm = 0; mm < 2; ++mm) {
            ushort4 hv, lv, l2v;
            unsigned short* hp  = (unsigned short*)&hv;
            unsigned short* lp  = (unsigned short*)&lv;
            unsigned short* l2p = (unsigned short*)&l2v;
#pragma unroll
            for (int j = 0; j < 4; ++j) split3(sv[mm][j], hp[j], lp[j], l2p[j]);
            int col = mm * 16 + quad * 4;
            *(ushort4*)&U[((w * 3 + 0) * 16 + mlane) * 40 + col] = hv;
            *(ushort4*)&U[((w * 3 + 1) * 16 + mlane) * 40 + col] = lv;
            *(ushort4*)&U[((w * 3 + 2) * 16 + mlane) * 40 + col] = l2v;
        }

        // ---- O^T += V^T·P^T, 6-term ----
        bf16_8 fp[3], fv[3][4];
#pragma unroll
        for (int p = 0; p < 3; ++p) {
            fp[p] = *(const bf16_8*)&U[((w * 3 + p) * 16 + mlane) * 40 + quad * 8];
#pragma unroll
            for (int mm = 0; mm < 4; ++mm)
                fv[p][mm] = *(const bf16_8*)&Vt[p][mm * 16 + mlane][quad * 8];
        }
#pragma unroll
        for (int s = 0; s < 6; ++s)
#pragma unroll
            for (int mm = 0; mm < 4; ++mm)
                oacc[mm] = __builtin_amdgcn_mfma_f32_16x16x32_bf16(
                    fv[ta[s]][mm], fp[tb[s]], oacc[mm], 0, 0, 0);
    }

    // ---- epilogue: lane holds q=mlane, d=mm*16+quad*4+j ----
    const float inv = 1.f / l_run;
    const size_t orow = (rowbase + qt * 64 + w * 16 + mlane) * 512 + colbase;
#pragma unroll
    for (int mm = 0; mm < 4; ++mm)
#pragma unroll
        for (int j = 0; j < 4; ++j)
            O[orow + mm * 16 + quad * 4 + j] = oacc[mm][j] * inv;
}

// ---------- compacted expert attention, zero-key correction, bf16 out = attn - meanV ----------
__global__ __launch_bounds__(256, 4)
void attn_compact_kernel(const float* __restrict__ Qc, const float* __restrict__ Kc,
                         const float* __restrict__ Vc, const float* __restrict__ meanV,
                         unsigned short* __restrict__ AOc, const int* __restrict__ OFF)
{
    const int qt = blockIdx.x & 15;
    const int h  = (blockIdx.x >> 4) & 7;
    const int e  = (blockIdx.x >> 7) & 3;
    const int b  = blockIdx.x >> 9;
    const int base = OFF[e * 8 + b];
    const int c    = OFF[e * 8 + b + 1] - base;
    if (qt * 64 >= c) return;
    const int nq = min(64, c - qt * 64);

    __shared__ float ks[64][68];
    __shared__ float vs[64][68];

    const int tid = threadIdx.x;
    const int q = tid >> 2, sub = tid & 3;
    const int ds = sub << 4;
    const int colbase = h * 64;
    const size_t qrow = (size_t)(base + qt * 64 + min(q, nq - 1)) * 512 + colbase;

    float4 qreg[4];
#pragma unroll
    for (int i = 0; i < 4; ++i) qreg[i] = *(const float4*)(Qc + qrow + ds + i * 4);

    float4 oacc[4];
#pragma unroll
    for (int i = 0; i < 4; ++i) { oacc[i].x = oacc[i].y = oacc[i].z = oacc[i].w = 0.f; }
    float m = -1e30f, l = 0.f;

    for (int kt = 0; kt * 64 < c; ++kt) {
        const int cmax = c - kt * 64 - 1;
        __syncthreads();
#pragma unroll
        for (int i = 0; i < 4; ++i) {
            int idx = tid + (i << 8);
            int r = idx >> 4, cc = (idx & 15) << 2;
            const size_t g = (size_t)(base + kt * 64 + min(r, cmax)) * 512 + colbase + cc;
            *(float4*)&ks[r][cc] = *(const float4*)(Kc + g);
            *(float4*)&vs[r][cc] = *(const float4*)(Vc + g);
        }
        __syncthreads();

#pragma unroll
        for (int ch = 0; ch < 4; ++ch) {
            float s[16];
#pragma unroll
            for (int jj = 0; jj < 16; ++jj) {
                const int j = (ch << 4) + jj;
                const float* kp = &ks[j][ds];
                float4 k0 = *(const float4*)kp;
                float4 k1 = *(const float4*)(kp + 4);
                float4 k2 = *(const float4*)(kp + 8);
                float4 k3 = *(const float4*)(kp + 12);
                float t = qreg[0].x * k0.x + qreg[0].y * k0.y + qreg[0].z * k0.z + qreg[0].w * k0.w
                        + qreg[1].x * k1.x + qreg[1].y * k1.y + qreg[1].z * k1.z + qreg[1].w * k1.w
                        + qreg[2].x * k2.x + qreg[2].y * k2.y + qreg[2].z * k2.z + qreg[2].w * k2.w
                        + qreg[3].x * k3.x + qreg[3].y * k3.y + qreg[3].z * k3.z + qreg[3].w * k3.w;
                t += __shfl_xor(t, 1);
                t += __shfl_xor(t, 2);
                s[jj] = (kt * 64 + j < c) ? t * 0.125f : -1e30f;
            }
            float mloc = s[0];
#pragma unroll
            for (int jj = 1; jj < 16; ++jj) mloc = fmaxf(mloc, s[jj]);
            float mnew = fmaxf(m, mloc);
            float alpha = __expf(m - mnew);
            float lt = 0.f;
#pragma unroll
            for (int jj = 0; jj < 16; ++jj) { s[jj] = __expf(s[jj] - mnew); lt += s[jj]; }
            l = l * alpha + lt;
#pragma unroll
            for (int i = 0; i < 4; ++i) {
                oacc[i].x *= alpha; oacc[i].y *= alpha;
                oacc[i].z *= alpha; oacc[i].w *= alpha;
            }
#pragma unroll
            for (int jj = 0; jj < 16; ++jj) {
                const float pj = s[jj];
                const float* vp = &vs[(ch << 4) + jj][ds];
#pragma unroll
                for (int i = 0; i < 4; ++i) {
                    float4 v = *(const float4*)(vp + i * 4);
                    oacc[i].x += pj * v.x; oacc[i].y += pj * v.y;
                    oacc[i].z += pj * v.z; oacc[i].w += pj * v.w;
                }
            }
            m = mnew;
        }
    }

    float mfin = (c < 1024) ? fmaxf(m, 0.f) : m;
    float alphaf = __expf(m - mfin);
    l = l * alphaf + (float)(1024 - c) * __expf(-mfin);
#pragma unroll
    for (int i = 0; i < 4; ++i) {
        oacc[i].x *= alphaf; oacc[i].y *= alphaf;
        oacc[i].z *= alphaf; oacc[i].w *= alphaf;
    }

    if (q < nq) {
        const float inv = 1.f / l;
        const size_t orow = (size_t)(base + qt * 64 + q) * 512 + colbase;
        const float* mv = meanV + e * 65536 + b * 512 + colbase + ds;
#pragma unroll
        for (int i = 0; i < 4; ++i) {
            float4 mvv = *(const float4*)(mv + i * 4);
            ushort4 o;
            o.x = f2bf(oacc[i].x * inv - mvv.x); o.y = f2bf(oacc[i].y * inv - mvv.y);
            o.z = f2bf(oacc[i].z * inv - mvv.z); o.w = f2bf(oacc[i].w * inv - mvv.w);
            *(ushort4*)&AOc[orow + ds + i * 4] = o;
        }
    }
}

// ---------- meanV per (b,e,h): M32[e][b][h*64+d] = sum(Vc rows)/1024 ----------
__global__ void sumv_kernel(const float* __restrict__ Vc, const int* __restrict__ OFF,
                            float* __restrict__ M32)
{
    const int h = blockIdx.x & 7, e = (blockIdx.x >> 3) & 3, b = blockIdx.x >> 5;
    const int base = OFF[e * 8 + b], c = OFF[e * 8 + b + 1] - base;
    const int tid = threadIdx.x;
    const int d = tid & 63, g = tid >> 6;
    float s = 0.f;
    for (int r = g; r < c; r += 4) s += Vc[(size_t)(base + r) * 512 + h * 64 + d];
    __shared__ float red[256];
    red[tid] = s;
    __syncthreads();
    if (g == 0)
        M32[e * 65536 + b * 512 + h * 64 + d] =
            (red[d] + red[64 + d] + red[128 + d] + red[192 + d]) * (1.f / 1024.f);
}

// ---------- embedding gather ----------
__global__ void gather_kernel(const int* __restrict__ tokens,
                              const float* __restrict__ emb,
                              float* __restrict__ X)
{
    const int t = blockIdx.x;
    const int tok = tokens[t];
    const float4* src = (const float4*)(emb + (size_t)tok * 512);
    float4* dst = (float4*)(X + (size_t)t * 512);
    dst[threadIdx.x] = src[threadIdx.x];
}

// ---------- gate + argmax ----------
__global__ __launch_bounds__(256)
void gate_kernel(const float* __restrict__ H, const float* __restrict__ Wg,
                 int* __restrict__ idx)
{
    const int t = blockIdx.x * 4 + (threadIdx.x >> 6);
    const int lane = threadIdx.x & 63;
    float a0 = 0, a1 = 0, a2 = 0, a3 = 0;
#pragma unroll
    for (int i = 0; i < 8; ++i) {
        int d = i * 64 + lane;
        float hv = H[(size_t)t * 512 + d];
        a0 += hv * Wg[d * 4 + 0];
        a1 += hv * Wg[d * 4 + 1];
        a2 += hv * Wg[d * 4 + 2];
        a3 += hv * Wg[d * 4 + 3];
    }
#pragma unroll
    for (int off = 32; off > 0; off >>= 1) {
        a0 += __shfl_down(a0, off);
        a1 += __shfl_down(a1, off);
        a2 += __shfl_down(a2, off);
        a3 += __shfl_down(a3, off);
    }
    if (lane == 0) {
        int best = 0; float bv = a0;
        if (a1 > bv) { bv = a1; best = 1; }
        if (a2 > bv) { bv = a2; best = 2; }
        if (a3 > bv) { bv = a3; best = 3; }
        idx[t] = best;
    }
}

// ---------- compaction: count / offsets / fill ----------
__global__ void count_kernel(const int* __restrict__ idx, int* __restrict__ cnt)
{
    const int t = blockIdx.x * 256 + threadIdx.x;
    atomicAdd(&cnt[idx[t] * 8 + (t >> 10)], 1);
}
__global__ void offsets_kernel(const int* __restrict__ cnt, int* __restrict__ OFF,
                               int* __restrict__ cursor)
{
    if (threadIdx.x == 0) {
        int a = 0;
        for (int i = 0; i < 32; ++i) { OFF[i] = a; cursor[i] = a; a += cnt[i]; }
        OFF[32] = a;
    }
}
__global__ void fill_kernel(const int* __restrict__ idx, int* __restrict__ cursor,
                            int* __restrict__ flat)
{
    const int t = blockIdx.x * 256 + threadIdx.x;
    const int p = atomicAdd(&cursor[idx[t] * 8 + (t >> 10)], 1);
    flat[p] = t;
}

// ---------- SB[b] = sum_e G2[e][b][:] . Wout ----------
__global__ void sb_kernel(const float* __restrict__ G2, const float* __restrict__ Wout,
                          float* __restrict__ SB)
{
    const int tid = threadIdx.x;
    const int pair = tid >> 3, t8 = tid & 7;
    const int e = pair >> 3, b = pair & 7;
    float s = 0.f;
    for (int d = t8; d < 512; d += 8) s += G2[e * 65536 + b * 512 + d] * Wout[d];
    __shared__ float red[256];
    __shared__ float red2[32];
    red[tid] = s;
    __syncthreads();
    if (tid < 32) {
        float t = 0.f;
#pragma unroll
        for (int k = 0; k < 8; ++k) t += red[tid * 8 + k];
        red2[tid] = t;
    }
    __syncthreads();
    if (tid < 8)
        SB[tid] = red2[tid] + red2[8 + tid] + red2[16 + tid] + red2[24 + tid];
}

// ---------- head: out[t] = OA[t,:].Wout + SB[b(t)] ----------
__global__ __launch_bounds__(256)
void wout_kernel(const float* __restrict__ OUT, const float* __restrict__ Wout,
                 const float* __restrict__ SB, float* __restrict__ out)
{
    const int t = blockIdx.x * 4 + (threadIdx.x >> 6);
    const int lane = threadIdx.x & 63;
    float s = 0.f;
#pragma unroll
    for (int i = 0; i < 8; ++i) {
        int d = i * 64 + lane;
        s += OUT[(size_t)t * 512 + d] * Wout[d];
    }
#pragma unroll
    for (int off = 32; off > 0; off >>= 1) s += __shfl_down(s, off);
    if (lane == 0) out[t] = s + SB[t >> 10];
}

// ---------- launch ----------
extern "C" void kernel_launch(void* const* d_in, const int* in_sizes, int n_in,
                              void* d_out, int out_size, void* d_ws, size_t ws_size,
                              hipStream_t stream)
{
    const int*   tokens = (const int*)d_in[0];
    const float* emb  = (const float*)d_in[1];
    const float* Wq   = (const float*)d_in[2];
    const float* Wk   = (const float*)d_in[3];
    const float* Wv   = (const float*)d_in[4];
    const float* Wo   = (const float*)d_in[5];
    const float* W1   = (const float*)d_in[6];
    const float* W2   = (const float*)d_in[7];
    const float* Wg   = (const float*)d_in[8];
    const float* eWq  = (const float*)d_in[9];
    const float* eWk  = (const float*)d_in[10];
    const float* eWv  = (const float*)d_in[11];
    const float* eWo  = (const float*)d_in[12];
    const float* eW1  = (const float*)d_in[13];
    const float* eW2  = (const float*)d_in[14];
    const float* Wout = (const float*)d_in[15];
    float* outp = (float*)d_out;

    float* WS = (float*)d_ws;
    const size_t SZ = (size_t)8192 * 512;
    float* P0 = WS, *P1 = WS + SZ, *P2 = WS + 2 * SZ, *P3 = WS + 3 * SZ, *P4 = WS + 4 * SZ;

    // weight planes (shorts) after the 5 f32 planes
    unsigned short* SP   = (unsigned short*)(WS + 5 * SZ);
    unsigned short* sW1p = SP;                      // [3][2048][512]
    unsigned short* sW2p = SP + 3145728;            // [3][512][2048]
    unsigned short* xWq  = SP + 6291456;            // [4][512][512]
    unsigned short* xWk  = xWq + 1048576;
    unsigned short* xWv  = xWk + 1048576;
    unsigned short* xWo  = xWv + 1048576;
    unsigned short* xW1  = xWo + 1048576;           // [4][2048][512]
    unsigned short* xW2  = xW1 + 4194304;           // [4][512][2048]

    float* MBase = WS + 5 * SZ + 9437184;           // misc region
    int* IDX    = (int*)MBase;
    int* cnt    = (int*)(MBase + 8192);
    int* OFFp   = (int*)(MBase + 8224);
    int* cursor = (int*)(MBase + 8264);
    int* flat   = (int*)(MBase + 8304);
    float* M32  = MBase + 16640;                    // [4][128][512]
    float* G0   = M32 + 262144;
    float* G2   = G0 + 262144;
    float* SB   = G2 + 262144;

    // shared-phase aliases
    float* X = P4, *Qb = P0, *Kb = P1, *Vb = P2, *AO = P3, *T0 = P4, *T1 = P0, *Hb = P4;
    // expert-phase aliases
    float* Qc = P0, *Kc = P1, *Vc = P2;
    unsigned short* AOc = (unsigned short*)P3;              // [8192][512] bf16 (P3a)
    unsigned short* T0c = (unsigned short*)(P3 + 2097152);  // [8192][512] bf16 (P3b)
    unsigned short* T1c = (unsigned short*)P0;              // [8192][2048] bf16 (P0..P1)
    float* G1 = P2;                                         // [4][128][2048]
    float* OA = P3;

    const int M = 8192, D = 512, FF = 2048;
    const size_t sDD = (size_t)D * D, sDF = (size_t)D * FF;
    const float* NUL = nullptr;
    float* NULm = nullptr;

    // ---- weight prep: transpose+split once per call (~20 us) ----
    wsplit_kernel<3><<<dim3(32, 8, 1),  256, 0, stream>>>(W1, NUL, NUL, NUL, sW1p, 0, 0, 0, D, FF, 1, 0, 0);
    wsplit_kernel<3><<<dim3(8, 32, 1),  256, 0, stream>>>(W2, NUL, NUL, NUL, sW2p, 0, 0, 0, FF, D, 1, 0, 0);
    wsplit_kernel<1><<<dim3(8, 8, 16),  256, 0, stream>>>(eWq, eWk, eWv, eWo, xWq, xWk, xWv, xWo, D, D, 4, sDD, 262144);
    wsplit_kernel<1><<<dim3(32, 8, 4),  256, 0, stream>>>(eW1, NUL, NUL, NUL, xW1, 0, 0, 0, D, FF, 4, sDF, 1048576);
    wsplit_kernel<1><<<dim3(8, 32, 4),  256, 0, stream>>>(eW2, NUL, NUL, NUL, xW2, 0, 0, 0, FF, D, 4, sDF, 1048576);

    // ---- shared block (argmax-safe, 6-term split) ----
    gather_kernel<<<8192, 128, 0, stream>>>(tokens, emb, X);
    gemm_kernel<6, 0, 0, 3, 0, 0, 0><<<dim3(64, 4, 3), 256, 0, stream>>>(
        X, Wq, Wk, Wv, Qb, Kb, Vb, M, D, D, 0, 0, 0, nullptr, nullptr);
    attn_kernel<<<1024, 256, 0, stream>>>(Qb, Kb, Vb, AO);
    gemm_kernel<6, 0, 0, 1, 0, 0, 0><<<dim3(64, 4, 1), 256, 0, stream>>>(
        AO, Wo, NUL, NUL, T0, NULm, NULm, M, D, D, 0, 0, 0, nullptr, nullptr);
    gemm_kernel<6, 0, 0, 1, 1, 0, 0><<<dim3(64, 16, 1), 256, 0, stream>>>(
        T0, sW1p, NUL, NUL, T1, NULm, NULm, M, FF, D, 0, 0, 0, nullptr, nullptr);
    gemm_kernel<6, 0, 0, 1, 1, 0, 0><<<dim3(64, 4, 1), 256, 0, stream>>>(
        T1, sW2p, NUL, NUL, Hb, NULm, NULm, M, D, FF, 0, 0, 0, nullptr, nullptr);
    gate_kernel<<<2048, 256, 0, stream>>>(Hb, Wg, IDX);

    // ---- compaction ----
    hipMemsetAsync(cnt, 0, 32 * sizeof(int), stream);
    hipMemsetAsync(M32, 0, 4 * 128 * 512 * sizeof(float), stream);
    count_kernel<<<32, 256, 0, stream>>>(IDX, cnt);
    offsets_kernel<<<1, 64, 0, stream>>>(cnt, OFFp, cursor);
    fill_kernel<<<32, 256, 0, stream>>>(IDX, cursor, flat);

    // ---- expert QKV (gather A=Hb f32, pre-split B planes, C f32 compact) ----
    gemm_kernel<1, 2, 1, 3, 1, 0, 0><<<dim3(64, 4, 12), 256, 0, stream>>>(
        Hb, xWq, xWk, xWv, Qc, Kc, Vc, M, D, D, 0, 262144, 0, OFFp, flat);
    sumv_kernel<<<256, 256, 0, stream>>>(Vc, OFFp, M32);
    attn_compact_kernel<<<4096, 256, 0, stream>>>(Qc, Kc, Vc, M32, AOc, OFFp);

    // ---- expert FFN chain (A bf16 direct, B planes, C bf16) ----
    gemm_kernel<1, 1, 1, 1, 1, 1, 1><<<dim3(64, 4, 4), 256, 0, stream>>>(
        AOc, xWo, NUL, NUL, T0c, NULm, NULm, M, D, D, 0, 262144, 0, OFFp, flat);
    gemm_kernel<1, 1, 1, 1, 1, 1, 1><<<dim3(64, 16, 4), 256, 0, stream>>>(
        T0c, xW1, NUL, NUL, T1c, NULm, NULm, M, FF, D, 0, 1048576, 0, OFFp, flat);

    // ---- meanV path (tiny, legacy f32-B kernel) ----
    gemm_kernel<1, 0, 0, 1, 0, 0, 0><<<dim3(1, 4, 4), 256, 0, stream>>>(
        M32, eWo, NUL, NUL, G0, NULm, NULm, 128, D, D, 65536, sDD, 65536, nullptr, nullptr);
    gemm_kernel<1, 0, 0, 1, 0, 0, 0><<<dim3(1, 16, 4), 256, 0, stream>>>(
        G0, eW1, NUL, NUL, G1, NULm, NULm, 128, FF, D, 65536, sDF, 262144, nullptr, nullptr);
    gemm_kernel<1, 0, 0, 1, 0, 0, 0><<<dim3(1, 4, 4), 256, 0, stream>>>(
        G1, eW2, NUL, NUL, G2, NULm, NULm, 128, D, FF, 262144, sDF, 65536, nullptr, nullptr);

    // ---- expert W2: A=T1c bf16, scatter f32 into OA ----
    gemm_kernel<1, 1, 2, 1, 1, 1, 0><<<dim3(64, 4, 4), 256, 0, stream>>>(
        T1c, xW2, NUL, NUL, OA, NULm, NULm, M, D, FF, 0, 1048576, 0, OFFp, flat);

    sb_kernel<<<1, 256, 0, stream>>>(G2, Wout, SB);
    wout_kernel<<<2048, 256, 0, stream>>>(OA, Wout, SB, outp);
}

// Round 2
// 1731.128 us; speedup vs baseline: 1.3117x; 1.1807x over previous
//
#include <hip/hip_runtime.h>
#include <stdint.h>
#include <stddef.h>

// ---------- types ----------
typedef __bf16 bf16_8 __attribute__((ext_vector_type(8)));
typedef float  f32x4  __attribute__((ext_vector_type(4)));

__device__ __forceinline__ unsigned short f2bf(float f) {
    unsigned u = __float_as_uint(f);
    unsigned r = (u + 0x7fffu + ((u >> 16) & 1u)) >> 16;   // RTN-even
    return (unsigned short)r;
}
__device__ __forceinline__ float bf2f(unsigned short s) {
    return __uint_as_float(((unsigned)s) << 16);
}
__device__ __forceinline__ void split3(float v, unsigned short& h, unsigned short& l, unsigned short& l2) {
    h = f2bf(v);
    float r1 = v - bf2f(h);
    l = f2bf(r1);
    l2 = f2bf(r1 - bf2f(l));
}
__device__ __forceinline__ void split2(float v, unsigned short& h, unsigned short& l) {
    h = f2bf(v);
    l = f2bf(v - bf2f(h));
}

// ---------- weight transpose+split: src [K][N] f32 -> dst planes [P][N][K] bf16 ----------
template<int P>
__global__ __launch_bounds__(256)
void wsplit_kernel(const float* __restrict__ s0, const float* __restrict__ s1,
                   const float* __restrict__ s2, const float* __restrict__ s3,
                   unsigned short* __restrict__ d0, unsigned short* __restrict__ d1,
                   unsigned short* __restrict__ d2, unsigned short* __restrict__ d3,
                   int K, int N, int nper, size_t sstride, size_t dstride)
{
    const int z = blockIdx.z;
    const int arr = z / nper, e = z - arr * nper;
    const float* src = (arr == 0 ? s0 : arr == 1 ? s1 : arr == 2 ? s2 : s3) + (size_t)e * sstride;
    unsigned short* dst = (arr == 0 ? d0 : arr == 1 ? d1 : arr == 2 ? d2 : d3) + (size_t)e * dstride;
    const size_t NK = (size_t)N * K;
    __shared__ float T[64][65];
    const int n0 = blockIdx.x * 64, k0 = blockIdx.y * 64;
    const int tid = threadIdx.x;
#pragma unroll
    for (int i = 0; i < 16; ++i) {
        int idx = tid + (i << 8);
        int kk = idx >> 6, nn = idx & 63;
        T[kk][nn] = src[(size_t)(k0 + kk) * N + n0 + nn];
    }
    __syncthreads();
#pragma unroll
    for (int i = 0; i < 4; ++i) {
        int idx = (tid + (i << 8)) << 2;
        int nn = idx >> 6, kk = idx & 63;
        ushort4 hv, lv, l2v;
        unsigned short* hp = (unsigned short*)&hv;
        unsigned short* lp = (unsigned short*)&lv;
        unsigned short* l2p = (unsigned short*)&l2v;
#pragma unroll
        for (int j = 0; j < 4; ++j) {
            float v = T[kk + j][nn];
            unsigned short h = f2bf(v);
            hp[j] = h;
            if (P == 3) {
                float r1 = v - bf2f(h);
                unsigned short l = f2bf(r1);
                lp[j] = l;
                l2p[j] = f2bf(r1 - bf2f(l));
            }
        }
        unsigned short* dp = dst + (size_t)(n0 + nn) * K + k0 + kk;
        *(ushort4*)dp = hv;
        if (P == 3) {
            *(ushort4*)(dp + NK) = lv;
            *(ushort4*)(dp + 2 * NK) = l2v;
        }
    }
}

// ---------- GEMM: C = A * B via bf16 MFMA, 128x128 tile, BK=32, expert-batched in z ----------
// TERMS=6: 3-term split both sides (fp32-grade). TERMS=1: plain bf16.
// AMODE: 0 direct (+e*astride); 1 compact base+row; 2 gather flat[base+row].
// CMODE: 0 direct (+e*cstride); 1 compact masked; 2 scatter flat[base+row] masked.
// BPRE: 0 = B f32 [K][N], in-loop split+transpose; 1 = B pre-split bf16 planes [P][N][K].
// A16:  0 = A f32, in-loop split; 1 = A bf16 [M][K], pure copy staging (TERMS must be 1).
// C16:  0 = C f32; 1 = C bf16.
template<int TERMS, int AMODE, int CMODE, int NW, int BPRE, int A16, int C16>
__global__ __launch_bounds__(256, 2)
void gemm_kernel(const void* __restrict__ Av,
                 const void* __restrict__ B0, const void* __restrict__ B1, const void* __restrict__ B2,
                 void* __restrict__ C0, void* __restrict__ C1, void* __restrict__ C2,
                 int M, int N, int K,
                 size_t astride, size_t bstride, size_t cstride,
                 const int* __restrict__ OFF, const int* __restrict__ flat)
{
    const int z = blockIdx.z;
    const int e = z / NW, w = z - e * NW;
    int base = 0, cnt = M;
    if (AMODE == 1 || AMODE == 2 || CMODE == 1 || CMODE == 2) {
        base = OFF[e * 8];
        cnt  = OFF[e * 8 + 8] - base;
        if ((int)blockIdx.x * 128 >= cnt) return;
    }
    const void* Bsel = (NW == 3 ? (w == 0 ? B0 : w == 1 ? B1 : B2) : B0);
    void*       Csel = (NW == 3 ? (w == 0 ? C0 : w == 1 ? C1 : C2) : C0);
    const float*          Af = (const float*)Av + (size_t)e * astride;
    const unsigned short* As = (const unsigned short*)Av;
    const float*          Bf = (const float*)Bsel + (size_t)e * bstride;
    const unsigned short* Bp = (const unsigned short*)Bsel + (size_t)e * bstride;
    float*          Cf = (float*)Csel + (size_t)e * cstride;
    unsigned short* Cs = (unsigned short*)Csel + (size_t)e * cstride;
    const size_t NKb = (size_t)N * K;

    constexpr int NPL = (TERMS == 6) ? 3 : 1;
    __shared__ unsigned short Asm[NPL][128 * 40];   // padded stride 40
    __shared__ unsigned short Bsm[NPL][128 * 40];   // Bsm[n][k]

    const int tid   = threadIdx.x;
    const int lane  = tid & 63;
    const int wid   = tid >> 6;
    const int wm    = wid & 1, wn = wid >> 1;
    const int mlane = lane & 15, quad = lane >> 4;
    const int row0  = blockIdx.x * 128;
    const int col0  = blockIdx.y * 128;

    f32x4 acc[4][4];
#pragma unroll
    for (int i = 0; i < 4; ++i)
#pragma unroll
        for (int j = 0; j < 4; ++j)
#pragma unroll
            for (int r = 0; r < 4; ++r) acc[i][j][r] = 0.f;

    for (int k0 = 0; k0 < K; k0 += 32) {
        // ---- stage A ----
        if (A16 == 0) {
#pragma unroll
            for (int i = 0; i < 4; ++i) {
                int idx = tid + (i << 8);
                int r = idx >> 3;
                int c = (idx & 7) << 2;
                int lr = row0 + r;
                if (AMODE != 0) lr = min(lr, cnt - 1);
                size_t arow = (AMODE == 2) ? (size_t)flat[base + lr]
                            : (AMODE == 1) ? (size_t)(base + lr) : (size_t)lr;
                const float4 a = *(const float4*)(Af + arow * K + k0 + c);
                float av[4] = {a.x, a.y, a.z, a.w};
                ushort4 hv, lv, l2v;
                unsigned short* hp  = (unsigned short*)&hv;
                unsigned short* lp  = (unsigned short*)&lv;
                unsigned short* l2p = (unsigned short*)&l2v;
#pragma unroll
                for (int j = 0; j < 4; ++j) {
                    unsigned short h = f2bf(av[j]);
                    hp[j] = h;
                    if (TERMS == 6) {
                        float r1 = av[j] - bf2f(h);
                        unsigned short l = f2bf(r1);
                        lp[j]  = l;
                        l2p[j] = f2bf(r1 - bf2f(l));
                    }
                }
                *(ushort4*)&Asm[0][r * 40 + c] = hv;
                if (TERMS == 6) {
                    *(ushort4*)&Asm[1][r * 40 + c] = lv;
                    *(ushort4*)&Asm[2][r * 40 + c] = l2v;
                }
            }
        } else {
#pragma unroll
            for (int j = 0; j < 2; ++j) {
                int c = tid * 2 + j;                 // 512 chunks of 8 shorts
                int r = c >> 2, q8 = (c & 3) << 3;
                int lr = row0 + r;
                if (AMODE != 0) lr = min(lr, cnt - 1);
                size_t arow = (AMODE == 2) ? (size_t)flat[base + lr]
                            : (AMODE == 1) ? (size_t)(base + lr) : (size_t)lr;
                *(uint4*)&Asm[0][r * 40 + q8] = *(const uint4*)(As + arow * K + k0 + q8);
            }
        }
        // ---- stage B ----
        if (BPRE == 0) {
#pragma unroll
            for (int i = 0; i < 2; ++i) {
                int idx = tid + (i << 8);
                int kk = idx >> 4;
                int n8 = (idx & 15) << 3;
                const float* bp = Bf + (size_t)(k0 + kk) * N + col0 + n8;
                const float4 b0 = *(const float4*)bp;
                const float4 b1 = *(const float4*)(bp + 4);
                float bv[8] = {b0.x, b0.y, b0.z, b0.w, b1.x, b1.y, b1.z, b1.w};
#pragma unroll
                for (int j = 0; j < 8; ++j) {
                    unsigned short h = f2bf(bv[j]);
                    Bsm[0][(n8 + j) * 40 + kk] = h;
                    if (TERMS == 6) {
                        float r1 = bv[j] - bf2f(h);
                        unsigned short l = f2bf(r1);
                        Bsm[1][(n8 + j) * 40 + kk] = l;
                        Bsm[2][(n8 + j) * 40 + kk] = f2bf(r1 - bf2f(l));
                    }
                }
            }
        } else {
#pragma unroll
            for (int p = 0; p < NPL; ++p)
#pragma unroll
                for (int j = 0; j < 2; ++j) {
                    int c = tid * 2 + j;
                    int r = c >> 2, q8 = (c & 3) << 3;
                    *(uint4*)&Bsm[p][r * 40 + q8] =
                        *(const uint4*)(Bp + (size_t)p * NKb + (size_t)(col0 + r) * K + k0 + q8);
                }
        }
        __syncthreads();

        bf16_8 fa[3][4], fb[3][4];
#pragma unroll
        for (int t = 0; t < 4; ++t) {
            int ar = (wm * 64 + t * 16 + mlane) * 40 + quad * 8;
            int br = (wn * 64 + t * 16 + mlane) * 40 + quad * 8;
            fa[0][t] = *(const bf16_8*)&Asm[0][ar];
            fb[0][t] = *(const bf16_8*)&Bsm[0][br];
            if (TERMS == 6) {
                fa[1][t] = *(const bf16_8*)&Asm[1][ar];
                fa[2][t] = *(const bf16_8*)&Asm[2][ar];
                fb[1][t] = *(const bf16_8*)&Bsm[1][br];
                fb[2][t] = *(const bf16_8*)&Bsm[2][br];
            }
        }
        const int ta[6] = {0, 0, 1, 0, 1, 2};
        const int tb[6] = {0, 1, 0, 2, 1, 0};
#pragma unroll
        for (int s = 0; s < TERMS; ++s)
#pragma unroll
            for (int mt = 0; mt < 4; ++mt)
#pragma unroll
                for (int nt = 0; nt < 4; ++nt)
                    acc[mt][nt] = __builtin_amdgcn_mfma_f32_16x16x32_bf16(
                        fa[ta[s]][mt], fb[tb[s]][nt], acc[mt][nt], 0, 0, 0);
        __syncthreads();
    }

    // ---- epilogue: C/D layout col=lane&15, row=quad*4+reg ----
#pragma unroll
    for (int mt = 0; mt < 4; ++mt)
#pragma unroll
        for (int nt = 0; nt < 4; ++nt) {
            int c = col0 + wn * 64 + nt * 16 + mlane;
#pragma unroll
            for (int j = 0; j < 4; ++j) {
                int lr = row0 + wm * 64 + mt * 16 + quad * 4 + j;
                if ((CMODE == 1 || CMODE == 2) && lr >= cnt) continue;
                size_t crow = (CMODE == 2) ? (size_t)flat[base + lr]
                            : (CMODE == 1) ? (size_t)(base + lr) : (size_t)lr;
                if (C16) Cs[crow * N + c] = f2bf(acc[mt][nt][j]);
                else     Cf[crow * N + c] = acc[mt][nt][j];
            }
        }
}

// ---------- MFMA split-bf16 flash attention (shared block), fp32-grade ----------
// 64 q per block (16 q per wave), KVBLK=32. Swapped operands:
//   S^T[key][q] = K·Q^T  (6-term, 3-plane split)  -> lane-local softmax per q-row
//   O^T[d][q]   = V^T·P^T (6-term, 3-plane split of P and V)
// LDS 60KB -> 2 blocks/CU. Replaces the fp32-VALU version that sat at the
// LDS-BW roofline (64x read amplification, 32GB LDS traffic = 464us floor).
__global__ __launch_bounds__(256, 2)
void attn_kernel(const float* __restrict__ Q, const float* __restrict__ Km,
                 const float* __restrict__ V, float* __restrict__ O)
{
    __shared__ __align__(16) unsigned short Ks[3][2][32][40];  // [plane][dchunk][key][dmod32+pad]
    __shared__ __align__(16) unsigned short Vt[3][64][40];     // [plane][d][key+pad]
    __shared__ __align__(16) unsigned short U[15360];          // Qs [3][2][64][40] / P [4][3][16][40]

    const int tid = threadIdx.x;
    const int lane = tid & 63;
    const int w = tid >> 6;
    const int mlane = lane & 15, quad = lane >> 4;

    const int qt = blockIdx.x & 15;
    const int h  = (blockIdx.x >> 4) & 7;
    const int b  = blockIdx.x >> 7;
    const size_t rowbase = (size_t)b * 1024;
    const int colbase = h * 64;

    // ---- stage Q tile (64 q x 64 d) as 3 bf16 planes ----
#pragma unroll
    for (int i = 0; i < 4; ++i) {
        int idx = tid + (i << 8);
        int r = idx >> 4, c4 = (idx & 15) << 2;
        const float4 a = *(const float4*)(Q + (rowbase + qt * 64 + r) * 512 + colbase + c4);
        float av[4] = {a.x, a.y, a.z, a.w};
        ushort4 hv, lv, l2v;
        unsigned short* hp  = (unsigned short*)&hv;
        unsigned short* lp  = (unsigned short*)&lv;
        unsigned short* l2p = (unsigned short*)&l2v;
#pragma unroll
        for (int j = 0; j < 4; ++j) split3(av[j], hp[j], lp[j], l2p[j]);
        int ch = c4 >> 5, cm = c4 & 31;
        *(ushort4*)&U[(((0 * 2 + ch) * 64) + r) * 40 + cm] = hv;
        *(ushort4*)&U[(((1 * 2 + ch) * 64) + r) * 40 + cm] = lv;
        *(ushort4*)&U[(((2 * 2 + ch) * 64) + r) * 40 + cm] = l2v;
    }
    __syncthreads();

    // Q B-fragments: col=q=w*16+mlane, k=d=c*32+quad*8+j  (persist in regs)
    bf16_8 fq[3][2];
#pragma unroll
    for (int p = 0; p < 3; ++p)
#pragma unroll
        for (int c = 0; c < 2; ++c)
            fq[p][c] = *(const bf16_8*)&U[(((p * 2 + c) * 64) + (w * 16 + mlane)) * 40 + quad * 8];
    __syncthreads();   // all waves done reading Qs before P region reuses U

    f32x4 oacc[4];     // O^T frags: d = mm*16+quad*4+j, q = mlane
#pragma unroll
    for (int i = 0; i < 4; ++i)
#pragma unroll
        for (int j = 0; j < 4; ++j) oacc[i][j] = 0.f;
    float m_run = -1e30f, l_run = 0.f;

    const int ta[6] = {0, 0, 1, 0, 1, 2};
    const int tb[6] = {0, 1, 0, 2, 1, 0};

    for (int tt = 0; tt < 32; ++tt) {
        __syncthreads();
        // ---- stage K tile (32 keys x 64 d), natural layout ----
#pragma unroll
        for (int i = 0; i < 2; ++i) {
            int idx = tid + (i << 8);
            int r = idx >> 4, c4 = (idx & 15) << 2;
            const float4 a = *(const float4*)(Km + (rowbase + tt * 32 + r) * 512 + colbase + c4);
            float av[4] = {a.x, a.y, a.z, a.w};
            ushort4 hv, lv, l2v;
            unsigned short* hp  = (unsigned short*)&hv;
            unsigned short* lp  = (unsigned short*)&lv;
            unsigned short* l2p = (unsigned short*)&l2v;
#pragma unroll
            for (int j = 0; j < 4; ++j) split3(av[j], hp[j], lp[j], l2p[j]);
            int ch = c4 >> 5, cm = c4 & 31;
            *(ushort4*)&Ks[0][ch][r][cm] = hv;
            *(ushort4*)&Ks[1][ch][r][cm] = lv;
            *(ushort4*)&Ks[2][ch][r][cm] = l2v;
        }
        // ---- stage V tile transposed: Vt[d][key] (coalesced dword loads) ----
#pragma unroll
        for (int i = 0; i < 2; ++i) {
            int idx = tid + (i << 8);
            int d = idx & 63, k4 = (idx >> 6) << 2;
            const float* vp = V + (rowbase + tt * 32 + k4) * 512 + colbase + d;
            float vv[4] = {vp[0], vp[512], vp[1024], vp[1536]};
            ushort4 hv, lv, l2v;
            unsigned short* hp  = (unsigned short*)&hv;
            unsigned short* lp  = (unsigned short*)&lv;
            unsigned short* l2p = (unsigned short*)&l2v;
#pragma unroll
            for (int j = 0; j < 4; ++j) split3(vv[j], hp[j], lp[j], l2p[j]);
            *(ushort4*)&Vt[0][d][k4] = hv;
            *(ushort4*)&Vt[1][d][k4] = lv;
            *(ushort4*)&Vt[2][d][k4] = l2v;
        }
        __syncthreads();

        // ---- S^T = K·Q^T, 6-term ----
        f32x4 sacc[2];
#pragma unroll
        for (int mm = 0; mm < 2; ++mm)
#pragma unroll
            for (int j = 0; j < 4; ++j) sacc[mm][j] = 0.f;
        bf16_8 fk[3][2][2];
#pragma unroll
        for (int p = 0; p < 3; ++p)
#pragma unroll
            for (int c = 0; c < 2; ++c)
#pragma unroll
                for (int mm = 0; mm < 2; ++mm)
                    fk[p][c][mm] = *(const bf16_8*)&Ks[p][c][mm * 16 + mlane][quad * 8];
#pragma unroll
        for (int s = 0; s < 6; ++s)
#pragma unroll
            for (int c = 0; c < 2; ++c)
#pragma unroll
                for (int mm = 0; mm < 2; ++mm)
                    sacc[mm] = __builtin_amdgcn_mfma_f32_16x16x32_bf16(
                        fk[ta[s]][c][mm], fq[tb[s]][c], sacc[mm], 0, 0, 0);

        // ---- online softmax: lane owns q=mlane, keys mm*16+quad*4+j ----
        float sv[2][4];
#pragma unroll
        for (int mm = 0; mm < 2; ++mm)
#pragma unroll
            for (int j = 0; j < 4; ++j) sv[mm][j] = sacc[mm][j] * 0.125f;
        float tmax = sv[0][0];
#pragma unroll
        for (int mm = 0; mm < 2; ++mm)
#pragma unroll
            for (int j = 0; j < 4; ++j) tmax = fmaxf(tmax, sv[mm][j]);
        tmax = fmaxf(tmax, __shfl_xor(tmax, 16));
        tmax = fmaxf(tmax, __shfl_xor(tmax, 32));
        float mnew = fmaxf(m_run, tmax);
        float alpha = __expf(m_run - mnew);
        float lsum = 0.f;
#pragma unroll
        for (int mm = 0; mm < 2; ++mm)
#pragma unroll
            for (int j = 0; j < 4; ++j) {
                float p = __expf(sv[mm][j] - mnew);
                sv[mm][j] = p;
                lsum += p;
            }
        lsum += __shfl_xor(lsum, 16);
        lsum += __shfl_xor(lsum, 32);
        l_run = l_run * alpha + lsum;
        m_run = mnew;
#pragma unroll
        for (int mm = 0; mm < 4; ++mm)
#pragma unroll
            for (int j = 0; j < 4; ++j) oacc[mm][j] *= alpha;

        // ---- split P to 3 bf16 planes, per-wave LDS round-trip ----
#pragma unroll
        for (int mm = 0; mm < 2; ++mm) {
            ushort4 hv, lv, l2v;
            unsigned short* hp  = (unsigned short*)&hv;
            unsigned short* lp  = (unsigned short*)&lv;
            unsigned short* l2p = (unsigned short*)&l2v;
#pragma unroll
            for (int j = 0; j < 4; ++j) split3(sv[mm][j], hp[j], lp[j], l2p[j]);
            int col = mm * 16 + quad * 4;
            *(ushort4*)&U[((w * 3 + 0) * 16 + mlane) * 40 + col] = hv;
            *(ushort4*)&U[((w * 3 + 1) * 16 + mlane) * 40 + col] = lv;
            *(ushort4*)&U[((w * 3 + 2) * 16 + mlane) * 40 + col] = l2v;
        }

        // ---- O^T += V^T·P^T, 6-term ----
        bf16_8 fp[3], fv[3][4];
#pragma unroll
        for (int p = 0; p < 3; ++p) {
            fp[p] = *(const bf16_8*)&U[((w * 3 + p) * 16 + mlane) * 40 + quad * 8];
#pragma unroll
            for (int mm = 0; mm < 4; ++mm)
                fv[p][mm] = *(const bf16_8*)&Vt[p][mm * 16 + mlane][quad * 8];
        }
#pragma unroll
        for (int s = 0; s < 6; ++s)
#pragma unroll
            for (int mm = 0; mm < 4; ++mm)
                oacc[mm] = __builtin_amdgcn_mfma_f32_16x16x32_bf16(
                    fv[ta[s]][mm], fp[tb[s]], oacc[mm], 0, 0, 0);
    }

    // ---- epilogue: lane holds q=mlane, d=mm*16+quad*4+j ----
    const float inv = 1.f / l_run;
    const size_t orow = (rowbase + qt * 64 + w * 16 + mlane) * 512 + colbase;
#pragma unroll
    for (int mm = 0; mm < 4; ++mm)
#pragma unroll
        for (int j = 0; j < 4; ++j)
            O[orow + mm * 16 + quad * 4 + j] = oacc[mm][j] * inv;
}

// ---------- MFMA split-bf16 compacted expert attention (3-term, 2-plane) ----------
// Same swapped-operand structure as attn_kernel; post-gate path is bf16-grade
// already, so 3 cross terms (h.h + h.l + l.h, err ~2^-17) suffice. Keeps the
// row-clamped staging, -1e30 key masking, zero-key denominator correction and
// meanV subtraction of the fp32 version it replaces (which was LDS-BW-bound:
// 476us, MfmaUtil=0). LDS 40KB -> 3 blocks/CU.
__global__ __launch_bounds__(256, 3)
void attn_compact_kernel(const float* __restrict__ Qc, const float* __restrict__ Kc,
                         const float* __restrict__ Vc, const float* __restrict__ meanV,
                         unsigned short* __restrict__ AOc, const int* __restrict__ OFF)
{
    const int qt = blockIdx.x & 15;
    const int h  = (blockIdx.x >> 4) & 7;
    const int e  = (blockIdx.x >> 7) & 3;
    const int b  = blockIdx.x >> 9;
    const int base = OFF[e * 8 + b];
    const int c    = OFF[e * 8 + b + 1] - base;
    if (qt * 64 >= c) return;
    const int nq = min(64, c - qt * 64);

    __shared__ __align__(16) unsigned short Ks[2][2][32][40];  // [plane][dchunk][key][dmod32+pad]
    __shared__ __align__(16) unsigned short Vt[2][64][40];     // [plane][d][key+pad]
    __shared__ __align__(16) unsigned short U[10240];          // Qs [2][2][64][40] / P [4][2][16][40]

    const int tid = threadIdx.x;
    const int lane = tid & 63;
    const int w = tid >> 6;
    const int mlane = lane & 15, quad = lane >> 4;
    const int colbase = h * 64;
    const int cmax = c - 1;

    // ---- stage Q tile (64 q x 64 d, row-clamped) as 2 bf16 planes ----
#pragma unroll
    for (int i = 0; i < 4; ++i) {
        int idx = tid + (i << 8);
        int r = idx >> 4, c4 = (idx & 15) << 2;
        const size_t g = (size_t)(base + min(qt * 64 + r, cmax)) * 512 + colbase + c4;
        const float4 a = *(const float4*)(Qc + g);
        float av[4] = {a.x, a.y, a.z, a.w};
        ushort4 hv, lv;
        unsigned short* hp = (unsigned short*)&hv;
        unsigned short* lp = (unsigned short*)&lv;
#pragma unroll
        for (int j = 0; j < 4; ++j) split2(av[j], hp[j], lp[j]);
        int ch = c4 >> 5, cm = c4 & 31;
        *(ushort4*)&U[(((0 * 2 + ch) * 64) + r) * 40 + cm] = hv;
        *(ushort4*)&U[(((1 * 2 + ch) * 64) + r) * 40 + cm] = lv;
    }
    __syncthreads();

    // Q B-fragments: col=q=w*16+mlane, k=d=c*32+quad*8+j (persist in regs)
    bf16_8 fq[2][2];
#pragma unroll
    for (int p = 0; p < 2; ++p)
#pragma unroll
        for (int cc = 0; cc < 2; ++cc)
            fq[p][cc] = *(const bf16_8*)&U[(((p * 2 + cc) * 64) + (w * 16 + mlane)) * 40 + quad * 8];
    __syncthreads();   // all waves done reading Qs before P region reuses U

    f32x4 oacc[4];     // O^T frags: d = mm*16+quad*4+j, q = mlane
#pragma unroll
    for (int i = 0; i < 4; ++i)
#pragma unroll
        for (int j = 0; j < 4; ++j) oacc[i][j] = 0.f;
    float m_run = -1e30f, l_run = 0.f;

    const int ta3[3] = {0, 0, 1};
    const int tb3[3] = {0, 1, 0};

    for (int kt = 0; kt * 32 < c; ++kt) {
        __syncthreads();
        // ---- stage K tile (32 keys x 64 d, row-clamped), 2 planes ----
#pragma unroll
        for (int i = 0; i < 2; ++i) {
            int idx = tid + (i << 8);
            int r = idx >> 4, c4 = (idx & 15) << 2;
            const size_t g = (size_t)(base + min(kt * 32 + r, cmax)) * 512 + colbase + c4;
            const float4 a = *(const float4*)(Kc + g);
            float av[4] = {a.x, a.y, a.z, a.w};
            ushort4 hv, lv;
            unsigned short* hp = (unsigned short*)&hv;
            unsigned short* lp = (unsigned short*)&lv;
#pragma unroll
            for (int j = 0; j < 4; ++j) split2(av[j], hp[j], lp[j]);
            int ch = c4 >> 5, cm = c4 & 31;
            *(ushort4*)&Ks[0][ch][r][cm] = hv;
            *(ushort4*)&Ks[1][ch][r][cm] = lv;
        }
        // ---- stage V tile transposed: Vt[d][key] (row-clamped coalesced loads) ----
#pragma unroll
        for (int i = 0; i < 2; ++i) {
            int idx = tid + (i << 8);
            int d = idx & 63, k4 = (idx >> 6) << 2;
            float vv[4];
#pragma unroll
            for (int j = 0; j < 4; ++j)
                vv[j] = Vc[(size_t)(base + min(kt * 32 + k4 + j, cmax)) * 512 + colbase + d];
            ushort4 hv, lv;
            unsigned short* hp = (unsigned short*)&hv;
            unsigned short* lp = (unsigned short*)&lv;
#pragma unroll
            for (int j = 0; j < 4; ++j) split2(vv[j], hp[j], lp[j]);
            *(ushort4*)&Vt[0][d][k4] = hv;
            *(ushort4*)&Vt[1][d][k4] = lv;
        }
        __syncthreads();

        // ---- S^T = K·Q^T, 3-term ----
        f32x4 sacc[2];
#pragma unroll
        for (int mm = 0; mm < 2; ++mm)
#pragma unroll
            for (int j = 0; j < 4; ++j) sacc[mm][j] = 0.f;
        bf16_8 fk[2][2][2];
#pragma unroll
        for (int p = 0; p < 2; ++p)
#pragma unroll
            for (int cc = 0; cc < 2; ++cc)
#pragma unroll
                for (int mm = 0; mm < 2; ++mm)
                    fk[p][cc][mm] = *(const bf16_8*)&Ks[p][cc][mm * 16 + mlane][quad * 8];
#pragma unroll
        for (int s = 0; s < 3; ++s)
#pragma unroll
            for (int cc = 0; cc < 2; ++cc)
#pragma unroll
                for (int mm = 0; mm < 2; ++mm)
                    sacc[mm] = __builtin_amdgcn_mfma_f32_16x16x32_bf16(
                        fk[ta3[s]][cc][mm], fq[tb3[s]][cc], sacc[mm], 0, 0, 0);

        // ---- online softmax with key masking: key = kt*32 + mm*16 + quad*4 + j ----
        float sv[2][4];
#pragma unroll
        for (int mm = 0; mm < 2; ++mm)
#pragma unroll
            for (int j = 0; j < 4; ++j) {
                int kg = kt * 32 + mm * 16 + quad * 4 + j;
                sv[mm][j] = (kg < c) ? sacc[mm][j] * 0.125f : -1e30f;
            }
        float tmax = sv[0][0];
#pragma unroll
        for (int mm = 0; mm < 2; ++mm)
#pragma unroll
            for (int j = 0; j < 4; ++j) tmax = fmaxf(tmax, sv[mm][j]);
        tmax = fmaxf(tmax, __shfl_xor(tmax, 16));
        tmax = fmaxf(tmax, __shfl_xor(tmax, 32));
        float mnew = fmaxf(m_run, tmax);
        float alpha = __expf(m_run - mnew);
        float lsum = 0.f;
#pragma unroll
        for (int mm = 0; mm < 2; ++mm)
#pragma unroll
            for (int j = 0; j < 4; ++j) {
                float p = __expf(sv[mm][j] - mnew);
                sv[mm][j] = p;
                lsum += p;
            }
        lsum += __shfl_xor(lsum, 16);
        lsum += __shfl_xor(lsum, 32);
        l_run = l_run * alpha + lsum;
        m_run = mnew;
#pragma unroll
        for (int mm = 0; mm < 4; ++mm)
#pragma unroll
            for (int j = 0; j < 4; ++j) oacc[mm][j] *= alpha;

        // ---- split P to 2 bf16 planes, per-wave LDS round-trip ----
#pragma unroll
        for (int mm = 0; mm < 2; ++mm) {
            ushort4 hv, lv;
            unsigned short* hp = (unsigned short*)&hv;
            unsigned short* lp = (unsigned short*)&lv;
#pragma unroll
            for (int j = 0; j < 4; ++j) split2(sv[mm][j], hp[j], lp[j]);
            int col = mm * 16 + quad * 4;
            *(ushort4*)&U[((w * 2 + 0) * 16 + mlane) * 40 + col] = hv;
            *(ushort4*)&U[((w * 2 + 1) * 16 + mlane) * 40 + col] = lv;
        }

        // ---- O^T += V^T·P^T, 3-term ----
        bf16_8 fp[2], fv[2][4];
#pragma unroll
        for (int p = 0; p < 2; ++p) {
            fp[p] = *(const bf16_8*)&U[((w * 2 + p) * 16 + mlane) * 40 + quad * 8];
#pragma unroll
            for (int mm = 0; mm < 4; ++mm)
                fv[p][mm] = *(const bf16_8*)&Vt[p][mm * 16 + mlane][quad * 8];
        }
#pragma unroll
        for (int s = 0; s < 3; ++s)
#pragma unroll
            for (int mm = 0; mm < 4; ++mm)
                oacc[mm] = __builtin_amdgcn_mfma_f32_16x16x32_bf16(
                    fv[ta3[s]][mm], fp[tb3[s]], oacc[mm], 0, 0, 0);
    }

    // ---- zero-key correction: (1024-c) keys with logit 0, value 0 ----
    float mfin = (c < 1024) ? fmaxf(m_run, 0.f) : m_run;
    float alphaf = __expf(m_run - mfin);
    l_run = l_run * alphaf + (float)(1024 - c) * __expf(-mfin);
#pragma unroll
    for (int mm = 0; mm < 4; ++mm)
#pragma unroll
        for (int j = 0; j < 4; ++j) oacc[mm][j] *= alphaf;

    // ---- epilogue: lane holds q=w*16+mlane, d=mm*16+quad*4+j; out = attn - meanV, bf16 ----
    const int qi = w * 16 + mlane;
    if (qi < nq) {
        const float inv = 1.f / l_run;
        const size_t orow = (size_t)(base + qt * 64 + qi) * 512 + colbase;
        const float* mv = meanV + e * 65536 + b * 512 + colbase;
#pragma unroll
        for (int mm = 0; mm < 4; ++mm) {
            int d0 = mm * 16 + quad * 4;
            ushort4 o;
            o.x = f2bf(oacc[mm][0] * inv - mv[d0 + 0]);
            o.y = f2bf(oacc[mm][1] * inv - mv[d0 + 1]);
            o.z = f2bf(oacc[mm][2] * inv - mv[d0 + 2]);
            o.w = f2bf(oacc[mm][3] * inv - mv[d0 + 3]);
            *(ushort4*)&AOc[orow + d0] = o;
        }
    }
}

// ---------- meanV per (b,e,h): M32[e][b][h*64+d] = sum(Vc rows)/1024 ----------
__global__ void sumv_kernel(const float* __restrict__ Vc, const int* __restrict__ OFF,
                            float* __restrict__ M32)
{
    const int h = blockIdx.x & 7, e = (blockIdx.x >> 3) & 3, b = blockIdx.x >> 5;
    const int base = OFF[e * 8 + b], c = OFF[e * 8 + b + 1] - base;
    const int tid = threadIdx.x;
    const int d = tid & 63, g = tid >> 6;
    float s = 0.f;
    for (int r = g; r < c; r += 4) s += Vc[(size_t)(base + r) * 512 + h * 64 + d];
    __shared__ float red[256];
    red[tid] = s;
    __syncthreads();
    if (g == 0)
        M32[e * 65536 + b * 512 + h * 64 + d] =
            (red[d] + red[64 + d] + red[128 + d] + red[192 + d]) * (1.f / 1024.f);
}

// ---------- embedding gather ----------
__global__ void gather_kernel(const int* __restrict__ tokens,
                              const float* __restrict__ emb,
                              float* __restrict__ X)
{
    const int t = blockIdx.x;
    const int tok = tokens[t];
    const float4* src = (const float4*)(emb + (size_t)tok * 512);
    float4* dst = (float4*)(X + (size_t)t * 512);
    dst[threadIdx.x] = src[threadIdx.x];
}

// ---------- gate + argmax ----------
__global__ __launch_bounds__(256)
void gate_kernel(const float* __restrict__ H, const float* __restrict__ Wg,
                 int* __restrict__ idx)
{
    const int t = blockIdx.x * 4 + (threadIdx.x >> 6);
    const int lane = threadIdx.x & 63;
    float a0 = 0, a1 = 0, a2 = 0, a3 = 0;
#pragma unroll
    for (int i = 0; i < 8; ++i) {
        int d = i * 64 + lane;
        float hv = H[(size_t)t * 512 + d];
        a0 += hv * Wg[d * 4 + 0];
        a1 += hv * Wg[d * 4 + 1];
        a2 += hv * Wg[d * 4 + 2];
        a3 += hv * Wg[d * 4 + 3];
    }
#pragma unroll
    for (int off = 32; off > 0; off >>= 1) {
        a0 += __shfl_down(a0, off);
        a1 += __shfl_down(a1, off);
        a2 += __shfl_down(a2, off);
        a3 += __shfl_down(a3, off);
    }
    if (lane == 0) {
        int best = 0; float bv = a0;
        if (a1 > bv) { bv = a1; best = 1; }
        if (a2 > bv) { bv = a2; best = 2; }
        if (a3 > bv) { bv = a3; best = 3; }
        idx[t] = best;
    }
}

// ---------- compaction: count / offsets / fill ----------
__global__ void count_kernel(const int* __restrict__ idx, int* __restrict__ cnt)
{
    const int t = blockIdx.x * 256 + threadIdx.x;
    atomicAdd(&cnt[idx[t] * 8 + (t >> 10)], 1);
}
__global__ void offsets_kernel(const int* __restrict__ cnt, int* __restrict__ OFF,
                               int* __restrict__ cursor)
{
    if (threadIdx.x == 0) {
        int a = 0;
        for (int i = 0; i < 32; ++i) { OFF[i] = a; cursor[i] = a; a += cnt[i]; }
        OFF[32] = a;
    }
}
__global__ void fill_kernel(const int* __restrict__ idx, int* __restrict__ cursor,
                            int* __restrict__ flat)
{
    const int t = blockIdx.x * 256 + threadIdx.x;
    const int p = atomicAdd(&cursor[idx[t] * 8 + (t >> 10)], 1);
    flat[p] = t;
}

// ---------- SB[b] = sum_e G2[e][b][:] . Wout ----------
__global__ void sb_kernel(const float* __restrict__ G2, const float* __restrict__ Wout,
                          float* __restrict__ SB)
{
    const int tid = threadIdx.x;
    const int pair = tid >> 3, t8 = tid & 7;
    const int e = pair >> 3, b = pair & 7;
    float s = 0.f;
    for (int d = t8; d < 512; d += 8) s += G2[e * 65536 + b * 512 + d] * Wout[d];
    __shared__ float red[256];
    __shared__ float red2[32];
    red[tid] = s;
    __syncthreads();
    if (tid < 32) {
        float t = 0.f;
#pragma unroll
        for (int k = 0; k < 8; ++k) t += red[tid * 8 + k];
        red2[tid] = t;
    }
    __syncthreads();
    if (tid < 8)
        SB[tid] = red2[tid] + red2[8 + tid] + red2[16 + tid] + red2[24 + tid];
}

// ---------- head: out[t] = OA[t,:].Wout + SB[b(t)] ----------
__global__ __launch_bounds__(256)
void wout_kernel(const float* __restrict__ OUT, const float* __restrict__ Wout,
                 const float* __restrict__ SB, float* __restrict__ out)
{
    const int t = blockIdx.x * 4 + (threadIdx.x >> 6);
    const int lane = threadIdx.x & 63;
    float s = 0.f;
#pragma unroll
    for (int i = 0; i < 8; ++i) {
        int d = i * 64 + lane;
        s += OUT[(size_t)t * 512 + d] * Wout[d];
    }
#pragma unroll
    for (int off = 32; off > 0; off >>= 1) s += __shfl_down(s, off);
    if (lane == 0) out[t] = s + SB[t >> 10];
}

// ---------- launch ----------
extern "C" void kernel_launch(void* const* d_in, const int* in_sizes, int n_in,
                              void* d_out, int out_size, void* d_ws, size_t ws_size,
                              hipStream_t stream)
{
    const int*   tokens = (const int*)d_in[0];
    const float* emb  = (const float*)d_in[1];
    const float* Wq   = (const float*)d_in[2];
    const float* Wk   = (const float*)d_in[3];
    const float* Wv   = (const float*)d_in[4];
    const float* Wo   = (const float*)d_in[5];
    const float* W1   = (const float*)d_in[6];
    const float* W2   = (const float*)d_in[7];
    const float* Wg   = (const float*)d_in[8];
    const float* eWq  = (const float*)d_in[9];
    const float* eWk  = (const float*)d_in[10];
    const float* eWv  = (const float*)d_in[11];
    const float* eWo  = (const float*)d_in[12];
    const float* eW1  = (const float*)d_in[13];
    const float* eW2  = (const float*)d_in[14];
    const float* Wout = (const float*)d_in[15];
    float* outp = (float*)d_out;

    float* WS = (float*)d_ws;
    const size_t SZ = (size_t)8192 * 512;
    float* P0 = WS, *P1 = WS + SZ, *P2 = WS + 2 * SZ, *P3 = WS + 3 * SZ, *P4 = WS + 4 * SZ;

    // weight planes (shorts) after the 5 f32 planes
    unsigned short* SP   = (unsigned short*)(WS + 5 * SZ);
    unsigned short* sW1p = SP;                      // [3][2048][512]
    unsigned short* sW2p = SP + 3145728;            // [3][512][2048]
    unsigned short* xWq  = SP + 6291456;            // [4][512][512]
    unsigned short* xWk  = xWq + 1048576;
    unsigned short* xWv  = xWk + 1048576;
    unsigned short* xWo  = xWv + 1048576;
    unsigned short* xW1  = xWo + 1048576;           // [4][2048][512]
    unsigned short* xW2  = xW1 + 4194304;           // [4][512][2048]

    float* MBase = WS + 5 * SZ + 9437184;           // misc region
    int* IDX    = (int*)MBase;
    int* cnt    = (int*)(MBase + 8192);
    int* OFFp   = (int*)(MBase + 8224);
    int* cursor = (int*)(MBase + 8264);
    int* flat   = (int*)(MBase + 8304);
    float* M32  = MBase + 16640;                    // [4][128][512]
    float* G0   = M32 + 262144;
    float* G2   = G0 + 262144;
    float* SB   = G2 + 262144;

    // shared-phase aliases
    float* X = P4, *Qb = P0, *Kb = P1, *Vb = P2, *AO = P3, *T0 = P4, *T1 = P0, *Hb = P4;
    // expert-phase aliases
    float* Qc = P0, *Kc = P1, *Vc = P2;
    unsigned short* AOc = (unsigned short*)P3;              // [8192][512] bf16 (P3a)
    unsigned short* T0c = (unsigned short*)(P3 + 2097152);  // [8192][512] bf16 (P3b)
    unsigned short* T1c = (unsigned short*)P0;              // [8192][2048] bf16 (P0..P1)
    float* G1 = P2;                                         // [4][128][2048]
    float* OA = P3;

    const int M = 8192, D = 512, FF = 2048;
    const size_t sDD = (size_t)D * D, sDF = (size_t)D * FF;
    const float* NUL = nullptr;
    float* NULm = nullptr;

    // ---- weight prep: transpose+split once per call (~20 us) ----
    wsplit_kernel<3><<<dim3(32, 8, 1),  256, 0, stream>>>(W1, NUL, NUL, NUL, sW1p, 0, 0, 0, D, FF, 1, 0, 0);
    wsplit_kernel<3><<<dim3(8, 32, 1),  256, 0, stream>>>(W2, NUL, NUL, NUL, sW2p, 0, 0, 0, FF, D, 1, 0, 0);
    wsplit_kernel<1><<<dim3(8, 8, 16),  256, 0, stream>>>(eWq, eWk, eWv, eWo, xWq, xWk, xWv, xWo, D, D, 4, sDD, 262144);
    wsplit_kernel<1><<<dim3(32, 8, 4),  256, 0, stream>>>(eW1, NUL, NUL, NUL, xW1, 0, 0, 0, D, FF, 4, sDF, 1048576);
    wsplit_kernel<1><<<dim3(8, 32, 4),  256, 0, stream>>>(eW2, NUL, NUL, NUL, xW2, 0, 0, 0, FF, D, 4, sDF, 1048576);

    // ---- shared block (argmax-safe, 6-term split) ----
    gather_kernel<<<8192, 128, 0, stream>>>(tokens, emb, X);
    gemm_kernel<6, 0, 0, 3, 0, 0, 0><<<dim3(64, 4, 3), 256, 0, stream>>>(
        X, Wq, Wk, Wv, Qb, Kb, Vb, M, D, D, 0, 0, 0, nullptr, nullptr);
    attn_kernel<<<1024, 256, 0, stream>>>(Qb, Kb, Vb, AO);
    gemm_kernel<6, 0, 0, 1, 0, 0, 0><<<dim3(64, 4, 1), 256, 0, stream>>>(
        AO, Wo, NUL, NUL, T0, NULm, NULm, M, D, D, 0, 0, 0, nullptr, nullptr);
    gemm_kernel<6, 0, 0, 1, 1, 0, 0><<<dim3(64, 16, 1), 256, 0, stream>>>(
        T0, sW1p, NUL, NUL, T1, NULm, NULm, M, FF, D, 0, 0, 0, nullptr, nullptr);
    gemm_kernel<6, 0, 0, 1, 1, 0, 0><<<dim3(64, 4, 1), 256, 0, stream>>>(
        T1, sW2p, NUL, NUL, Hb, NULm, NULm, M, D, FF, 0, 0, 0, nullptr, nullptr);
    gate_kernel<<<2048, 256, 0, stream>>>(Hb, Wg, IDX);

    // ---- compaction ----
    hipMemsetAsync(cnt, 0, 32 * sizeof(int), stream);
    hipMemsetAsync(M32, 0, 4 * 128 * 512 * sizeof(float), stream);
    count_kernel<<<32, 256, 0, stream>>>(IDX, cnt);
    offsets_kernel<<<1, 64, 0, stream>>>(cnt, OFFp, cursor);
    fill_kernel<<<32, 256, 0, stream>>>(IDX, cursor, flat);

    // ---- expert QKV (gather A=Hb f32, pre-split B planes, C f32 compact) ----
    gemm_kernel<1, 2, 1, 3, 1, 0, 0><<<dim3(64, 4, 12), 256, 0, stream>>>(
        Hb, xWq, xWk, xWv, Qc, Kc, Vc, M, D, D, 0, 262144, 0, OFFp, flat);
    sumv_kernel<<<256, 256, 0, stream>>>(Vc, OFFp, M32);
    attn_compact_kernel<<<4096, 256, 0, stream>>>(Qc, Kc, Vc, M32, AOc, OFFp);

    // ---- expert FFN chain (A bf16 direct, B planes, C bf16) ----
    gemm_kernel<1, 1, 1, 1, 1, 1, 1><<<dim3(64, 4, 4), 256, 0, stream>>>(
        AOc, xWo, NUL, NUL, T0c, NULm, NULm, M, D, D, 0, 262144, 0, OFFp, flat);
    gemm_kernel<1, 1, 1, 1, 1, 1, 1><<<dim3(64, 16, 4), 256, 0, stream>>>(
        T0c, xW1, NUL, NUL, T1c, NULm, NULm, M, FF, D, 0, 1048576, 0, OFFp, flat);

    // ---- meanV path (tiny, legacy f32-B kernel) ----
    gemm_kernel<1, 0, 0, 1, 0, 0, 0><<<dim3(1, 4, 4), 256, 0, stream>>>(
        M32, eWo, NUL, NUL, G0, NULm, NULm, 128, D, D, 65536, sDD, 65536, nullptr, nullptr);
    gemm_kernel<1, 0, 0, 1, 0, 0, 0><<<dim3(1, 16, 4), 256, 0, stream>>>(
        G0, eW1, NUL, NUL, G1, NULm, NULm, 128, FF, D, 65536, sDF, 262144, nullptr, nullptr);
    gemm_kernel<1, 0, 0, 1, 0, 0, 0><<<dim3(1, 4, 4), 256, 0, stream>>>(
        G1, eW2, NUL, NUL, G2, NULm, NULm, 128, D, FF, 262144, sDF, 65536, nullptr, nullptr);

    // ---- expert W2: A=T1c bf16, scatter f32 into OA ----
    gemm_kernel<1, 1, 2, 1, 1, 1, 0><<<dim3(64, 4, 4), 256, 0, stream>>>(
        T1c, xW2, NUL, NUL, OA, NULm, NULm, M, D, FF, 0, 1048576, 0, OFFp, flat);

    sb_kernel<<<1, 256, 0, stream>>>(G2, Wout, SB);
    wout_kernel<<<2048, 256, 0, stream>>>(OA, Wout, SB, outp);
}

// Round 3
// 1509.835 us; speedup vs baseline: 1.5039x; 1.1466x over previous
//
#include <hip/hip_runtime.h>
#include <stdint.h>
#include <stddef.h>

// ---------- types ----------
typedef __bf16 bf16_8 __attribute__((ext_vector_type(8)));
typedef float  f32x4  __attribute__((ext_vector_type(4)));

__device__ __forceinline__ unsigned short f2bf(float f) {
    unsigned u = __float_as_uint(f);
    unsigned r = (u + 0x7fffu + ((u >> 16) & 1u)) >> 16;   // RTN-even
    return (unsigned short)r;
}
__device__ __forceinline__ float bf2f(unsigned short s) {
    return __uint_as_float(((unsigned)s) << 16);
}
__device__ __forceinline__ void split3(float v, unsigned short& h, unsigned short& l, unsigned short& l2) {
    h = f2bf(v);
    float r1 = v - bf2f(h);
    l = f2bf(r1);
    l2 = f2bf(r1 - bf2f(l));
}
__device__ __forceinline__ void split2(float v, unsigned short& h, unsigned short& l) {
    h = f2bf(v);
    l = f2bf(v - bf2f(h));
}

// ---------- weight transpose+split: src [K][N] f32 -> dst planes [P][N][K] bf16 ----------
template<int P>
__global__ __launch_bounds__(256)
void wsplit_kernel(const float* __restrict__ s0, const float* __restrict__ s1,
                   const float* __restrict__ s2, const float* __restrict__ s3,
                   unsigned short* __restrict__ d0, unsigned short* __restrict__ d1,
                   unsigned short* __restrict__ d2, unsigned short* __restrict__ d3,
                   int K, int N, int nper, size_t sstride, size_t dstride)
{
    const int z = blockIdx.z;
    const int arr = z / nper, e = z - arr * nper;
    const float* src = (arr == 0 ? s0 : arr == 1 ? s1 : arr == 2 ? s2 : s3) + (size_t)e * sstride;
    unsigned short* dst = (arr == 0 ? d0 : arr == 1 ? d1 : arr == 2 ? d2 : d3) + (size_t)e * dstride;
    const size_t NK = (size_t)N * K;
    __shared__ float T[64][65];
    const int n0 = blockIdx.x * 64, k0 = blockIdx.y * 64;
    const int tid = threadIdx.x;
#pragma unroll
    for (int i = 0; i < 16; ++i) {
        int idx = tid + (i << 8);
        int kk = idx >> 6, nn = idx & 63;
        T[kk][nn] = src[(size_t)(k0 + kk) * N + n0 + nn];
    }
    __syncthreads();
#pragma unroll
    for (int i = 0; i < 4; ++i) {
        int idx = (tid + (i << 8)) << 2;
        int nn = idx >> 6, kk = idx & 63;
        ushort4 hv, lv, l2v;
        unsigned short* hp = (unsigned short*)&hv;
        unsigned short* lp = (unsigned short*)&lv;
        unsigned short* l2p = (unsigned short*)&l2v;
#pragma unroll
        for (int j = 0; j < 4; ++j) {
            float v = T[kk + j][nn];
            unsigned short h = f2bf(v);
            hp[j] = h;
            if (P == 3) {
                float r1 = v - bf2f(h);
                unsigned short l = f2bf(r1);
                lp[j] = l;
                l2p[j] = f2bf(r1 - bf2f(l));
            }
        }
        unsigned short* dp = dst + (size_t)(n0 + nn) * K + k0 + kk;
        *(ushort4*)dp = hv;
        if (P == 3) {
            *(ushort4*)(dp + NK) = lv;
            *(ushort4*)(dp + 2 * NK) = l2v;
        }
    }
}

// ---------- GEMM: C = A * B via bf16 MFMA, 128x128 tile, BK=32, expert-batched in z ----------
// TERMS=6: 3-term split both sides (fp32-grade). TERMS=1: plain bf16.
// AMODE: 0 direct (+e*astride); 1 compact base+row; 2 gather flat[base+row].
// CMODE: 0 direct (+e*cstride); 1 compact masked; 2 scatter flat[base+row] masked.
// BPRE: 0 = B f32 [K][N], in-loop split+transpose; 1 = B pre-split bf16 planes [P][N][K].
// A16:  0 = A f32, in-loop split; 1 = A bf16 [M][K], pure copy staging (TERMS must be 1).
// C16:  0 = C f32; 1 = C bf16.
template<int TERMS, int AMODE, int CMODE, int NW, int BPRE, int A16, int C16>
__global__ __launch_bounds__(256, 2)
void gemm_kernel(const void* __restrict__ Av,
                 const void* __restrict__ B0, const void* __restrict__ B1, const void* __restrict__ B2,
                 void* __restrict__ C0, void* __restrict__ C1, void* __restrict__ C2,
                 int M, int N, int K,
                 size_t astride, size_t bstride, size_t cstride,
                 const int* __restrict__ OFF, const int* __restrict__ flat)
{
    const int z = blockIdx.z;
    const int e = z / NW, w = z - e * NW;
    int base = 0, cnt = M;
    if (AMODE == 1 || AMODE == 2 || CMODE == 1 || CMODE == 2) {
        base = OFF[e * 8];
        cnt  = OFF[e * 8 + 8] - base;
        if ((int)blockIdx.x * 128 >= cnt) return;
    }
    const void* Bsel = (NW == 3 ? (w == 0 ? B0 : w == 1 ? B1 : B2) : B0);
    void*       Csel = (NW == 3 ? (w == 0 ? C0 : w == 1 ? C1 : C2) : C0);
    const float*          Af = (const float*)Av + (size_t)e * astride;
    const unsigned short* As = (const unsigned short*)Av;
    const float*          Bf = (const float*)Bsel + (size_t)e * bstride;
    const unsigned short* Bp = (const unsigned short*)Bsel + (size_t)e * bstride;
    float*          Cf = (float*)Csel + (size_t)e * cstride;
    unsigned short* Cs = (unsigned short*)Csel + (size_t)e * cstride;
    const size_t NKb = (size_t)N * K;

    constexpr int NPL = (TERMS == 6) ? 3 : 1;
    __shared__ unsigned short Asm[NPL][128 * 40];   // padded stride 40
    __shared__ unsigned short Bsm[NPL][128 * 40];   // Bsm[n][k]

    const int tid   = threadIdx.x;
    const int lane  = tid & 63;
    const int wid   = tid >> 6;
    const int wm    = wid & 1, wn = wid >> 1;
    const int mlane = lane & 15, quad = lane >> 4;
    const int row0  = blockIdx.x * 128;
    const int col0  = blockIdx.y * 128;

    f32x4 acc[4][4];
#pragma unroll
    for (int i = 0; i < 4; ++i)
#pragma unroll
        for (int j = 0; j < 4; ++j)
#pragma unroll
            for (int r = 0; r < 4; ++r) acc[i][j][r] = 0.f;

    for (int k0 = 0; k0 < K; k0 += 32) {
        // ---- stage A ----
        if (A16 == 0) {
#pragma unroll
            for (int i = 0; i < 4; ++i) {
                int idx = tid + (i << 8);
                int r = idx >> 3;
                int c = (idx & 7) << 2;
                int lr = row0 + r;
                if (AMODE != 0) lr = min(lr, cnt - 1);
                size_t arow = (AMODE == 2) ? (size_t)flat[base + lr]
                            : (AMODE == 1) ? (size_t)(base + lr) : (size_t)lr;
                const float4 a = *(const float4*)(Af + arow * K + k0 + c);
                float av[4] = {a.x, a.y, a.z, a.w};
                ushort4 hv, lv, l2v;
                unsigned short* hp  = (unsigned short*)&hv;
                unsigned short* lp  = (unsigned short*)&lv;
                unsigned short* l2p = (unsigned short*)&l2v;
#pragma unroll
                for (int j = 0; j < 4; ++j) {
                    unsigned short h = f2bf(av[j]);
                    hp[j] = h;
                    if (TERMS == 6) {
                        float r1 = av[j] - bf2f(h);
                        unsigned short l = f2bf(r1);
                        lp[j]  = l;
                        l2p[j] = f2bf(r1 - bf2f(l));
                    }
                }
                *(ushort4*)&Asm[0][r * 40 + c] = hv;
                if (TERMS == 6) {
                    *(ushort4*)&Asm[1][r * 40 + c] = lv;
                    *(ushort4*)&Asm[2][r * 40 + c] = l2v;
                }
            }
        } else {
#pragma unroll
            for (int j = 0; j < 2; ++j) {
                int c = tid * 2 + j;                 // 512 chunks of 8 shorts
                int r = c >> 2, q8 = (c & 3) << 3;
                int lr = row0 + r;
                if (AMODE != 0) lr = min(lr, cnt - 1);
                size_t arow = (AMODE == 2) ? (size_t)flat[base + lr]
                            : (AMODE == 1) ? (size_t)(base + lr) : (size_t)lr;
                *(uint4*)&Asm[0][r * 40 + q8] = *(const uint4*)(As + arow * K + k0 + q8);
            }
        }
        // ---- stage B ----
        if (BPRE == 0) {
#pragma unroll
            for (int i = 0; i < 2; ++i) {
                int idx = tid + (i << 8);
                int kk = idx >> 4;
                int n8 = (idx & 15) << 3;
                const float* bp = Bf + (size_t)(k0 + kk) * N + col0 + n8;
                const float4 b0 = *(const float4*)bp;
                const float4 b1 = *(const float4*)(bp + 4);
                float bv[8] = {b0.x, b0.y, b0.z, b0.w, b1.x, b1.y, b1.z, b1.w};
#pragma unroll
                for (int j = 0; j < 8; ++j) {
                    unsigned short h = f2bf(bv[j]);
                    Bsm[0][(n8 + j) * 40 + kk] = h;
                    if (TERMS == 6) {
                        float r1 = bv[j] - bf2f(h);
                        unsigned short l = f2bf(r1);
                        Bsm[1][(n8 + j) * 40 + kk] = l;
                        Bsm[2][(n8 + j) * 40 + kk] = f2bf(r1 - bf2f(l));
                    }
                }
            }
        } else {
#pragma unroll
            for (int p = 0; p < NPL; ++p)
#pragma unroll
                for (int j = 0; j < 2; ++j) {
                    int c = tid * 2 + j;
                    int r = c >> 2, q8 = (c & 3) << 3;
                    *(uint4*)&Bsm[p][r * 40 + q8] =
                        *(const uint4*)(Bp + (size_t)p * NKb + (size_t)(col0 + r) * K + k0 + q8);
                }
        }
        __syncthreads();

        bf16_8 fa[3][4], fb[3][4];
#pragma unroll
        for (int t = 0; t < 4; ++t) {
            int ar = (wm * 64 + t * 16 + mlane) * 40 + quad * 8;
            int br = (wn * 64 + t * 16 + mlane) * 40 + quad * 8;
            fa[0][t] = *(const bf16_8*)&Asm[0][ar];
            fb[0][t] = *(const bf16_8*)&Bsm[0][br];
            if (TERMS == 6) {
                fa[1][t] = *(const bf16_8*)&Asm[1][ar];
                fa[2][t] = *(const bf16_8*)&Asm[2][ar];
                fb[1][t] = *(const bf16_8*)&Bsm[1][br];
                fb[2][t] = *(const bf16_8*)&Bsm[2][br];
            }
        }
        const int ta[6] = {0, 0, 1, 0, 1, 2};
        const int tb[6] = {0, 1, 0, 2, 1, 0};
#pragma unroll
        for (int s = 0; s < TERMS; ++s)
#pragma unroll
            for (int mt = 0; mt < 4; ++mt)
#pragma unroll
                for (int nt = 0; nt < 4; ++nt)
                    acc[mt][nt] = __builtin_amdgcn_mfma_f32_16x16x32_bf16(
                        fa[ta[s]][mt], fb[tb[s]][nt], acc[mt][nt], 0, 0, 0);
        __syncthreads();
    }

    // ---- epilogue: C/D layout col=lane&15, row=quad*4+reg ----
#pragma unroll
    for (int mt = 0; mt < 4; ++mt)
#pragma unroll
        for (int nt = 0; nt < 4; ++nt) {
            int c = col0 + wn * 64 + nt * 16 + mlane;
#pragma unroll
            for (int j = 0; j < 4; ++j) {
                int lr = row0 + wm * 64 + mt * 16 + quad * 4 + j;
                if ((CMODE == 1 || CMODE == 2) && lr >= cnt) continue;
                size_t crow = (CMODE == 2) ? (size_t)flat[base + lr]
                            : (CMODE == 1) ? (size_t)(base + lr) : (size_t)lr;
                if (C16) Cs[crow * N + c] = f2bf(acc[mt][nt][j]);
                else     Cf[crow * N + c] = acc[mt][nt][j];
            }
        }
}

// ---------- meanV FFN chain: out[e][b][n] (+)= sum_k in[e][b][k]*W[e][k][n], b<8 ----------
// Replaces the M=128 MFMA gemm launches that were latency-bound (212us @ 0.7% occupancy,
// 2.16M LDS bank conflicts). grid (N/64, K/512, E), block = 64 n-lanes x 4 k-groups.
// Weights read exactly once, coalesced 256B/wave/iter; full fp32 (more precise than the
// plain-bf16 path it replaces). K=512 -> direct store; K=2048 -> 4 chunks + atomicAdd
// (out pre-zeroed).
__global__ __launch_bounds__(256)
void meanv_gemm_kernel(const float* __restrict__ in, const float* __restrict__ W,
                       float* __restrict__ out, int N, int K,
                       size_t instride, size_t wstride, size_t outstride)
{
    const int e  = blockIdx.z;
    const int nl = threadIdx.x & 63;
    const int kg = threadIdx.x >> 6;
    const int n  = blockIdx.x * 64 + nl;
    const int k0 = blockIdx.y * 512;

    const float* inp = in + (size_t)e * instride + k0;
    const float* wp  = W + (size_t)e * wstride + (size_t)(k0 + kg * 128) * N + n;

    __shared__ float mv[8][512];
    for (int i = threadIdx.x; i < 4096; i += 256) {
        int b = i >> 9, k = i & 511;
        mv[b][k] = inp[(size_t)b * K + k];
    }
    __syncthreads();

    float acc[8] = {0.f, 0.f, 0.f, 0.f, 0.f, 0.f, 0.f, 0.f};
#pragma unroll 8
    for (int k = 0; k < 128; ++k) {
        float wv = wp[(size_t)k * N];
        const float* mk = &mv[0][kg * 128 + k];
#pragma unroll
        for (int b = 0; b < 8; ++b) acc[b] += mk[b * 512] * wv;
    }

    __shared__ float red[4][8][64];
#pragma unroll
    for (int b = 0; b < 8; ++b) red[kg][b][nl] = acc[b];
    __syncthreads();
    if (kg == 0) {
        float* op = out + (size_t)e * outstride + n;
#pragma unroll
        for (int b = 0; b < 8; ++b) {
            float s = red[0][b][nl] + red[1][b][nl] + red[2][b][nl] + red[3][b][nl];
            if (gridDim.y == 1) op[(size_t)b * N] = s;
            else                atomicAdd(&op[(size_t)b * N], s);
        }
    }
}

// ---------- MFMA split-bf16 flash attention (shared block), fp32-grade ----------
// 64 q per block (16 q per wave), KVBLK=32. Swapped operands:
//   S^T[key][q] = K·Q^T  (6-term, 3-plane split)  -> lane-local softmax per q-row
//   O^T[d][q]   = V^T·P^T (6-term, 3-plane split of P and V)
// LDS 60KB -> 2 blocks/CU. Replaces the fp32-VALU version that sat at the
// LDS-BW roofline (64x read amplification, 32GB LDS traffic = 464us floor).
__global__ __launch_bounds__(256, 2)
void attn_kernel(const float* __restrict__ Q, const float* __restrict__ Km,
                 const float* __restrict__ V, float* __restrict__ O)
{
    __shared__ __align__(16) unsigned short Ks[3][2][32][40];  // [plane][dchunk][key][dmod32+pad]
    __shared__ __align__(16) unsigned short Vt[3][64][40];     // [plane][d][key+pad]
    __shared__ __align__(16) unsigned short U[15360];          // Qs [3][2][64][40] / P [4][3][16][40]

    const int tid = threadIdx.x;
    const int lane = tid & 63;
    const int w = tid >> 6;
    const int mlane = lane & 15, quad = lane >> 4;

    const int qt = blockIdx.x & 15;
    const int h  = (blockIdx.x >> 4) & 7;
    const int b  = blockIdx.x >> 7;
    const size_t rowbase = (size_t)b * 1024;
    const int colbase = h * 64;

    // ---- stage Q tile (64 q x 64 d) as 3 bf16 planes ----
#pragma unroll
    for (int i = 0; i < 4; ++i) {
        int idx = tid + (i << 8);
        int r = idx >> 4, c4 = (idx & 15) << 2;
        const float4 a = *(const float4*)(Q + (rowbase + qt * 64 + r) * 512 + colbase + c4);
        float av[4] = {a.x, a.y, a.z, a.w};
        ushort4 hv, lv, l2v;
        unsigned short* hp  = (unsigned short*)&hv;
        unsigned short* lp  = (unsigned short*)&lv;
        unsigned short* l2p = (unsigned short*)&l2v;
#pragma unroll
        for (int j = 0; j < 4; ++j) split3(av[j], hp[j], lp[j], l2p[j]);
        int ch = c4 >> 5, cm = c4 & 31;
        *(ushort4*)&U[(((0 * 2 + ch) * 64) + r) * 40 + cm] = hv;
        *(ushort4*)&U[(((1 * 2 + ch) * 64) + r) * 40 + cm] = lv;
        *(ushort4*)&U[(((2 * 2 + ch) * 64) + r) * 40 + cm] = l2v;
    }
    __syncthreads();

    // Q B-fragments: col=q=w*16+mlane, k=d=c*32+quad*8+j  (persist in regs)
    bf16_8 fq[3][2];
#pragma unroll
    for (int p = 0; p < 3; ++p)
#pragma unroll
        for (int c = 0; c < 2; ++c)
            fq[p][c] = *(const bf16_8*)&U[(((p * 2 + c) * 64) + (w * 16 + mlane)) * 40 + quad * 8];
    __syncthreads();   // all waves done reading Qs before P region reuses U

    f32x4 oacc[4];     // O^T frags: d = mm*16+quad*4+j, q = mlane
#pragma unroll
    for (int i = 0; i < 4; ++i)
#pragma unroll
        for (int j = 0; j < 4; ++j) oacc[i][j] = 0.f;
    float m_run = -1e30f, l_run = 0.f;

    const int ta[6] = {0, 0, 1, 0, 1, 2};
    const int tb[6] = {0, 1, 0, 2, 1, 0};

    for (int tt = 0; tt < 32; ++tt) {
        __syncthreads();
        // ---- stage K tile (32 keys x 64 d), natural layout ----
#pragma unroll
        for (int i = 0; i < 2; ++i) {
            int idx = tid + (i << 8);
            int r = idx >> 4, c4 = (idx & 15) << 2;
            const float4 a = *(const float4*)(Km + (rowbase + tt * 32 + r) * 512 + colbase + c4);
            float av[4] = {a.x, a.y, a.z, a.w};
            ushort4 hv, lv, l2v;
            unsigned short* hp  = (unsigned short*)&hv;
            unsigned short* lp  = (unsigned short*)&lv;
            unsigned short* l2p = (unsigned short*)&l2v;
#pragma unroll
            for (int j = 0; j < 4; ++j) split3(av[j], hp[j], lp[j], l2p[j]);
            int ch = c4 >> 5, cm = c4 & 31;
            *(ushort4*)&Ks[0][ch][r][cm] = hv;
            *(ushort4*)&Ks[1][ch][r][cm] = lv;
            *(ushort4*)&Ks[2][ch][r][cm] = l2v;
        }
        // ---- stage V tile transposed: Vt[d][key] (coalesced dword loads) ----
#pragma unroll
        for (int i = 0; i < 2; ++i) {
            int idx = tid + (i << 8);
            int d = idx & 63, k4 = (idx >> 6) << 2;
            const float* vp = V + (rowbase + tt * 32 + k4) * 512 + colbase + d;
            float vv[4] = {vp[0], vp[512], vp[1024], vp[1536]};
            ushort4 hv, lv, l2v;
            unsigned short* hp  = (unsigned short*)&hv;
            unsigned short* lp  = (unsigned short*)&lv;
            unsigned short* l2p = (unsigned short*)&l2v;
#pragma unroll
            for (int j = 0; j < 4; ++j) split3(vv[j], hp[j], lp[j], l2p[j]);
            *(ushort4*)&Vt[0][d][k4] = hv;
            *(ushort4*)&Vt[1][d][k4] = lv;
            *(ushort4*)&Vt[2][d][k4] = l2v;
        }
        __syncthreads();

        // ---- S^T = K·Q^T, 6-term ----
        f32x4 sacc[2];
#pragma unroll
        for (int mm = 0; mm < 2; ++mm)
#pragma unroll
            for (int j = 0; j < 4; ++j) sacc[mm][j] = 0.f;
        bf16_8 fk[3][2][2];
#pragma unroll
        for (int p = 0; p < 3; ++p)
#pragma unroll
            for (int c = 0; c < 2; ++c)
#pragma unroll
                for (int mm = 0; mm < 2; ++mm)
                    fk[p][c][mm] = *(const bf16_8*)&Ks[p][c][mm * 16 + mlane][quad * 8];
#pragma unroll
        for (int s = 0; s < 6; ++s)
#pragma unroll
            for (int c = 0; c < 2; ++c)
#pragma unroll
                for (int mm = 0; mm < 2; ++mm)
                    sacc[mm] = __builtin_amdgcn_mfma_f32_16x16x32_bf16(
                        fk[ta[s]][c][mm], fq[tb[s]][c], sacc[mm], 0, 0, 0);

        // ---- online softmax: lane owns q=mlane, keys mm*16+quad*4+j ----
        float sv[2][4];
#pragma unroll
        for (int mm = 0; mm < 2; ++mm)
#pragma unroll
            for (int j = 0; j < 4; ++j) sv[mm][j] = sacc[mm][j] * 0.125f;
        float tmax = sv[0][0];
#pragma unroll
        for (int mm = 0; mm < 2; ++mm)
#pragma unroll
            for (int j = 0; j < 4; ++j) tmax = fmaxf(tmax, sv[mm][j]);
        tmax = fmaxf(tmax, __shfl_xor(tmax, 16));
        tmax = fmaxf(tmax, __shfl_xor(tmax, 32));
        float mnew = fmaxf(m_run, tmax);
        float alpha = __expf(m_run - mnew);
        float lsum = 0.f;
#pragma unroll
        for (int mm = 0; mm < 2; ++mm)
#pragma unroll
            for (int j = 0; j < 4; ++j) {
                float p = __expf(sv[mm][j] - mnew);
                sv[mm][j] = p;
                lsum += p;
            }
        lsum += __shfl_xor(lsum, 16);
        lsum += __shfl_xor(lsum, 32);
        l_run = l_run * alpha + lsum;
        m_run = mnew;
#pragma unroll
        for (int mm = 0; mm < 4; ++mm)
#pragma unroll
            for (int j = 0; j < 4; ++j) oacc[mm][j] *= alpha;

        // ---- split P to 3 bf16 planes, per-wave LDS round-trip ----
#pragma unroll
        for (int mm = 0; mm < 2; ++mm) {
            ushort4 hv, lv, l2v;
            unsigned short* hp  = (unsigned short*)&hv;
            unsigned short* lp  = (unsigned short*)&lv;
            unsigned short* l2p = (unsigned short*)&l2v;
#pragma unroll
            for (int j = 0; j < 4; ++j) split3(sv[mm][j], hp[j], lp[j], l2p[j]);
            int col = mm * 16 + quad * 4;
            *(ushort4*)&U[((w * 3 + 0) * 16 + mlane) * 40 + col] = hv;
            *(ushort4*)&U[((w * 3 + 1) * 16 + mlane) * 40 + col] = lv;
            *(ushort4*)&U[((w * 3 + 2) * 16 + mlane) * 40 + col] = l2v;
        }

        // ---- O^T += V^T·P^T, 6-term ----
        bf16_8 fp[3], fv[3][4];
#pragma unroll
        for (int p = 0; p < 3; ++p) {
            fp[p] = *(const bf16_8*)&U[((w * 3 + p) * 16 + mlane) * 40 + quad * 8];
#pragma unroll
            for (int mm = 0; mm < 4; ++mm)
                fv[p][mm] = *(const bf16_8*)&Vt[p][mm * 16 + mlane][quad * 8];
        }
#pragma unroll
        for (int s = 0; s < 6; ++s)
#pragma unroll
            for (int mm = 0; mm < 4; ++mm)
                oacc[mm] = __builtin_amdgcn_mfma_f32_16x16x32_bf16(
                    fv[ta[s]][mm], fp[tb[s]], oacc[mm], 0, 0, 0);
    }

    // ---- epilogue: lane holds q=mlane, d=mm*16+quad*4+j ----
    const float inv = 1.f / l_run;
    const size_t orow = (rowbase + qt * 64 + w * 16 + mlane) * 512 + colbase;
#pragma unroll
    for (int mm = 0; mm < 4; ++mm)
#pragma unroll
        for (int j = 0; j < 4; ++j)
            O[orow + mm * 16 + quad * 4 + j] = oacc[mm][j] * inv;
}

// ---------- MFMA split-bf16 compacted expert attention (3-term, 2-plane) ----------
// Same swapped-operand structure as attn_kernel; post-gate path is bf16-grade
// already, so 3 cross terms (h.h + h.l + l.h, err ~2^-17) suffice. Keeps the
// row-clamped staging, -1e30 key masking, zero-key denominator correction and
// meanV subtraction of the fp32 version it replaces (which was LDS-BW-bound:
// 476us, MfmaUtil=0). LDS 40KB -> 3 blocks/CU.
__global__ __launch_bounds__(256, 3)
void attn_compact_kernel(const float* __restrict__ Qc, const float* __restrict__ Kc,
                         const float* __restrict__ Vc, const float* __restrict__ meanV,
                         unsigned short* __restrict__ AOc, const int* __restrict__ OFF)
{
    const int qt = blockIdx.x & 15;
    const int h  = (blockIdx.x >> 4) & 7;
    const int e  = (blockIdx.x >> 7) & 3;
    const int b  = blockIdx.x >> 9;
    const int base = OFF[e * 8 + b];
    const int c    = OFF[e * 8 + b + 1] - base;
    if (qt * 64 >= c) return;
    const int nq = min(64, c - qt * 64);

    __shared__ __align__(16) unsigned short Ks[2][2][32][40];  // [plane][dchunk][key][dmod32+pad]
    __shared__ __align__(16) unsigned short Vt[2][64][40];     // [plane][d][key+pad]
    __shared__ __align__(16) unsigned short U[10240];          // Qs [2][2][64][40] / P [4][2][16][40]

    const int tid = threadIdx.x;
    const int lane = tid & 63;
    const int w = tid >> 6;
    const int mlane = lane & 15, quad = lane >> 4;
    const int colbase = h * 64;
    const int cmax = c - 1;

    // ---- stage Q tile (64 q x 64 d, row-clamped) as 2 bf16 planes ----
#pragma unroll
    for (int i = 0; i < 4; ++i) {
        int idx = tid + (i << 8);
        int r = idx >> 4, c4 = (idx & 15) << 2;
        const size_t g = (size_t)(base + min(qt * 64 + r, cmax)) * 512 + colbase + c4;
        const float4 a = *(const float4*)(Qc + g);
        float av[4] = {a.x, a.y, a.z, a.w};
        ushort4 hv, lv;
        unsigned short* hp = (unsigned short*)&hv;
        unsigned short* lp = (unsigned short*)&lv;
#pragma unroll
        for (int j = 0; j < 4; ++j) split2(av[j], hp[j], lp[j]);
        int ch = c4 >> 5, cm = c4 & 31;
        *(ushort4*)&U[(((0 * 2 + ch) * 64) + r) * 40 + cm] = hv;
        *(ushort4*)&U[(((1 * 2 + ch) * 64) + r) * 40 + cm] = lv;
    }
    __syncthreads();

    // Q B-fragments: col=q=w*16+mlane, k=d=c*32+quad*8+j (persist in regs)
    bf16_8 fq[2][2];
#pragma unroll
    for (int p = 0; p < 2; ++p)
#pragma unroll
        for (int cc = 0; cc < 2; ++cc)
            fq[p][cc] = *(const bf16_8*)&U[(((p * 2 + cc) * 64) + (w * 16 + mlane)) * 40 + quad * 8];
    __syncthreads();   // all waves done reading Qs before P region reuses U

    f32x4 oacc[4];     // O^T frags: d = mm*16+quad*4+j, q = mlane
#pragma unroll
    for (int i = 0; i < 4; ++i)
#pragma unroll
        for (int j = 0; j < 4; ++j) oacc[i][j] = 0.f;
    float m_run = -1e30f, l_run = 0.f;

    const int ta3[3] = {0, 0, 1};
    const int tb3[3] = {0, 1, 0};

    for (int kt = 0; kt * 32 < c; ++kt) {
        __syncthreads();
        // ---- stage K tile (32 keys x 64 d, row-clamped), 2 planes ----
#pragma unroll
        for (int i = 0; i < 2; ++i) {
            int idx = tid + (i << 8);
            int r = idx >> 4, c4 = (idx & 15) << 2;
            const size_t g = (size_t)(base + min(kt * 32 + r, cmax)) * 512 + colbase + c4;
            const float4 a = *(const float4*)(Kc + g);
            float av[4] = {a.x, a.y, a.z, a.w};
            ushort4 hv, lv;
            unsigned short* hp = (unsigned short*)&hv;
            unsigned short* lp = (unsigned short*)&lv;
#pragma unroll
            for (int j = 0; j < 4; ++j) split2(av[j], hp[j], lp[j]);
            int ch = c4 >> 5, cm = c4 & 31;
            *(ushort4*)&Ks[0][ch][r][cm] = hv;
            *(ushort4*)&Ks[1][ch][r][cm] = lv;
        }
        // ---- stage V tile transposed: Vt[d][key] (row-clamped coalesced loads) ----
#pragma unroll
        for (int i = 0; i < 2; ++i) {
            int idx = tid + (i << 8);
            int d = idx & 63, k4 = (idx >> 6) << 2;
            float vv[4];
#pragma unroll
            for (int j = 0; j < 4; ++j)
                vv[j] = Vc[(size_t)(base + min(kt * 32 + k4 + j, cmax)) * 512 + colbase + d];
            ushort4 hv, lv;
            unsigned short* hp = (unsigned short*)&hv;
            unsigned short* lp = (unsigned short*)&lv;
#pragma unroll
            for (int j = 0; j < 4; ++j) split2(vv[j], hp[j], lp[j]);
            *(ushort4*)&Vt[0][d][k4] = hv;
            *(ushort4*)&Vt[1][d][k4] = lv;
        }
        __syncthreads();

        // ---- S^T = K·Q^T, 3-term ----
        f32x4 sacc[2];
#pragma unroll
        for (int mm = 0; mm < 2; ++mm)
#pragma unroll
            for (int j = 0; j < 4; ++j) sacc[mm][j] = 0.f;
        bf16_8 fk[2][2][2];
#pragma unroll
        for (int p = 0; p < 2; ++p)
#pragma unroll
            for (int cc = 0; cc < 2; ++cc)
#pragma unroll
                for (int mm = 0; mm < 2; ++mm)
                    fk[p][cc][mm] = *(const bf16_8*)&Ks[p][cc][mm * 16 + mlane][quad * 8];
#pragma unroll
        for (int s = 0; s < 3; ++s)
#pragma unroll
            for (int cc = 0; cc < 2; ++cc)
#pragma unroll
                for (int mm = 0; mm < 2; ++mm)
                    sacc[mm] = __builtin_amdgcn_mfma_f32_16x16x32_bf16(
                        fk[ta3[s]][cc][mm], fq[tb3[s]][cc], sacc[mm], 0, 0, 0);

        // ---- online softmax with key masking: key = kt*32 + mm*16 + quad*4 + j ----
        float sv[2][4];
#pragma unroll
        for (int mm = 0; mm < 2; ++mm)
#pragma unroll
            for (int j = 0; j < 4; ++j) {
                int kg = kt * 32 + mm * 16 + quad * 4 + j;
                sv[mm][j] = (kg < c) ? sacc[mm][j] * 0.125f : -1e30f;
            }
        float tmax = sv[0][0];
#pragma unroll
        for (int mm = 0; mm < 2; ++mm)
#pragma unroll
            for (int j = 0; j < 4; ++j) tmax = fmaxf(tmax, sv[mm][j]);
        tmax = fmaxf(tmax, __shfl_xor(tmax, 16));
        tmax = fmaxf(tmax, __shfl_xor(tmax, 32));
        float mnew = fmaxf(m_run, tmax);
        float alpha = __expf(m_run - mnew);
        float lsum = 0.f;
#pragma unroll
        for (int mm = 0; mm < 2; ++mm)
#pragma unroll
            for (int j = 0; j < 4; ++j) {
                float p = __expf(sv[mm][j] - mnew);
                sv[mm][j] = p;
                lsum += p;
            }
        lsum += __shfl_xor(lsum, 16);
        lsum += __shfl_xor(lsum, 32);
        l_run = l_run * alpha + lsum;
        m_run = mnew;
#pragma unroll
        for (int mm = 0; mm < 4; ++mm)
#pragma unroll
            for (int j = 0; j < 4; ++j) oacc[mm][j] *= alpha;

        // ---- split P to 2 bf16 planes, per-wave LDS round-trip ----
#pragma unroll
        for (int mm = 0; mm < 2; ++mm) {
            ushort4 hv, lv;
            unsigned short* hp = (unsigned short*)&hv;
            unsigned short* lp = (unsigned short*)&lv;
#pragma unroll
            for (int j = 0; j < 4; ++j) split2(sv[mm][j], hp[j], lp[j]);
            int col = mm * 16 + quad * 4;
            *(ushort4*)&U[((w * 2 + 0) * 16 + mlane) * 40 + col] = hv;
            *(ushort4*)&U[((w * 2 + 1) * 16 + mlane) * 40 + col] = lv;
        }

        // ---- O^T += V^T·P^T, 3-term ----
        bf16_8 fp[2], fv[2][4];
#pragma unroll
        for (int p = 0; p < 2; ++p) {
            fp[p] = *(const bf16_8*)&U[((w * 2 + p) * 16 + mlane) * 40 + quad * 8];
#pragma unroll
            for (int mm = 0; mm < 4; ++mm)
                fv[p][mm] = *(const bf16_8*)&Vt[p][mm * 16 + mlane][quad * 8];
        }
#pragma unroll
        for (int s = 0; s < 3; ++s)
#pragma unroll
            for (int mm = 0; mm < 4; ++mm)
                oacc[mm] = __builtin_amdgcn_mfma_f32_16x16x32_bf16(
                    fv[ta3[s]][mm], fp[tb3[s]], oacc[mm], 0, 0, 0);
    }

    // ---- zero-key correction: (1024-c) keys with logit 0, value 0 ----
    float mfin = (c < 1024) ? fmaxf(m_run, 0.f) : m_run;
    float alphaf = __expf(m_run - mfin);
    l_run = l_run * alphaf + (float)(1024 - c) * __expf(-mfin);
#pragma unroll
    for (int mm = 0; mm < 4; ++mm)
#pragma unroll
        for (int j = 0; j < 4; ++j) oacc[mm][j] *= alphaf;

    // ---- epilogue: lane holds q=w*16+mlane, d=mm*16+quad*4+j; out = attn - meanV, bf16 ----
    const int qi = w * 16 + mlane;
    if (qi < nq) {
        const float inv = 1.f / l_run;
        const size_t orow = (size_t)(base + qt * 64 + qi) * 512 + colbase;
        const float* mv = meanV + e * 65536 + b * 512 + colbase;
#pragma unroll
        for (int mm = 0; mm < 4; ++mm) {
            int d0 = mm * 16 + quad * 4;
            ushort4 o;
            o.x = f2bf(oacc[mm][0] * inv - mv[d0 + 0]);
            o.y = f2bf(oacc[mm][1] * inv - mv[d0 + 1]);
            o.z = f2bf(oacc[mm][2] * inv - mv[d0 + 2]);
            o.w = f2bf(oacc[mm][3] * inv - mv[d0 + 3]);
            *(ushort4*)&AOc[orow + d0] = o;
        }
    }
}

// ---------- meanV per (b,e,h): M32[e][b][h*64+d] = sum(Vc rows)/1024 ----------
__global__ void sumv_kernel(const float* __restrict__ Vc, const int* __restrict__ OFF,
                            float* __restrict__ M32)
{
    const int h = blockIdx.x & 7, e = (blockIdx.x >> 3) & 3, b = blockIdx.x >> 5;
    const int base = OFF[e * 8 + b], c = OFF[e * 8 + b + 1] - base;
    const int tid = threadIdx.x;
    const int d = tid & 63, g = tid >> 6;
    float s = 0.f;
    for (int r = g; r < c; r += 4) s += Vc[(size_t)(base + r) * 512 + h * 64 + d];
    __shared__ float red[256];
    red[tid] = s;
    __syncthreads();
    if (g == 0)
        M32[e * 65536 + b * 512 + h * 64 + d] =
            (red[d] + red[64 + d] + red[128 + d] + red[192 + d]) * (1.f / 1024.f);
}

// ---------- embedding gather ----------
__global__ void gather_kernel(const int* __restrict__ tokens,
                              const float* __restrict__ emb,
                              float* __restrict__ X)
{
    const int t = blockIdx.x;
    const int tok = tokens[t];
    const float4* src = (const float4*)(emb + (size_t)tok * 512);
    float4* dst = (float4*)(X + (size_t)t * 512);
    dst[threadIdx.x] = src[threadIdx.x];
}

// ---------- gate + argmax ----------
__global__ __launch_bounds__(256)
void gate_kernel(const float* __restrict__ H, const float* __restrict__ Wg,
                 int* __restrict__ idx)
{
    const int t = blockIdx.x * 4 + (threadIdx.x >> 6);
    const int lane = threadIdx.x & 63;
    float a0 = 0, a1 = 0, a2 = 0, a3 = 0;
#pragma unroll
    for (int i = 0; i < 8; ++i) {
        int d = i * 64 + lane;
        float hv = H[(size_t)t * 512 + d];
        a0 += hv * Wg[d * 4 + 0];
        a1 += hv * Wg[d * 4 + 1];
        a2 += hv * Wg[d * 4 + 2];
        a3 += hv * Wg[d * 4 + 3];
    }
#pragma unroll
    for (int off = 32; off > 0; off >>= 1) {
        a0 += __shfl_down(a0, off);
        a1 += __shfl_down(a1, off);
        a2 += __shfl_down(a2, off);
        a3 += __shfl_down(a3, off);
    }
    if (lane == 0) {
        int best = 0; float bv = a0;
        if (a1 > bv) { bv = a1; best = 1; }
        if (a2 > bv) { bv = a2; best = 2; }
        if (a3 > bv) { bv = a3; best = 3; }
        idx[t] = best;
    }
}

// ---------- compaction: count / offsets / fill ----------
__global__ void count_kernel(const int* __restrict__ idx, int* __restrict__ cnt)
{
    const int t = blockIdx.x * 256 + threadIdx.x;
    atomicAdd(&cnt[idx[t] * 8 + (t >> 10)], 1);
}
__global__ void offsets_kernel(const int* __restrict__ cnt, int* __restrict__ OFF,
                               int* __restrict__ cursor)
{
    if (threadIdx.x == 0) {
        int a = 0;
        for (int i = 0; i < 32; ++i) { OFF[i] = a; cursor[i] = a; a += cnt[i]; }
        OFF[32] = a;
    }
}
__global__ void fill_kernel(const int* __restrict__ idx, int* __restrict__ cursor,
                            int* __restrict__ flat)
{
    const int t = blockIdx.x * 256 + threadIdx.x;
    const int p = atomicAdd(&cursor[idx[t] * 8 + (t >> 10)], 1);
    flat[p] = t;
}

// ---------- SB[b] = sum_e G2[e][b][:] . Wout ----------
__global__ void sb_kernel(const float* __restrict__ G2, const float* __restrict__ Wout,
                          float* __restrict__ SB)
{
    const int tid = threadIdx.x;
    const int pair = tid >> 3, t8 = tid & 7;
    const int e = pair >> 3, b = pair & 7;
    float s = 0.f;
    for (int d = t8; d < 512; d += 8) s += G2[e * 65536 + b * 512 + d] * Wout[d];
    __shared__ float red[256];
    __shared__ float red2[32];
    red[tid] = s;
    __syncthreads();
    if (tid < 32) {
        float t = 0.f;
#pragma unroll
        for (int k = 0; k < 8; ++k) t += red[tid * 8 + k];
        red2[tid] = t;
    }
    __syncthreads();
    if (tid < 8)
        SB[tid] = red2[tid] + red2[8 + tid] + red2[16 + tid] + red2[24 + tid];
}

// ---------- head: out[t] = OA[t,:].Wout + SB[b(t)] ----------
__global__ __launch_bounds__(256)
void wout_kernel(const float* __restrict__ OUT, const float* __restrict__ Wout,
                 const float* __restrict__ SB, float* __restrict__ out)
{
    const int t = blockIdx.x * 4 + (threadIdx.x >> 6);
    const int lane = threadIdx.x & 63;
    float s = 0.f;
#pragma unroll
    for (int i = 0; i < 8; ++i) {
        int d = i * 64 + lane;
        s += OUT[(size_t)t * 512 + d] * Wout[d];
    }
#pragma unroll
    for (int off = 32; off > 0; off >>= 1) s += __shfl_down(s, off);
    if (lane == 0) out[t] = s + SB[t >> 10];
}

// ---------- launch ----------
extern "C" void kernel_launch(void* const* d_in, const int* in_sizes, int n_in,
                              void* d_out, int out_size, void* d_ws, size_t ws_size,
                              hipStream_t stream)
{
    const int*   tokens = (const int*)d_in[0];
    const float* emb  = (const float*)d_in[1];
    const float* Wq   = (const float*)d_in[2];
    const float* Wk   = (const float*)d_in[3];
    const float* Wv   = (const float*)d_in[4];
    const float* Wo   = (const float*)d_in[5];
    const float* W1   = (const float*)d_in[6];
    const float* W2   = (const float*)d_in[7];
    const float* Wg   = (const float*)d_in[8];
    const float* eWq  = (const float*)d_in[9];
    const float* eWk  = (const float*)d_in[10];
    const float* eWv  = (const float*)d_in[11];
    const float* eWo  = (const float*)d_in[12];
    const float* eW1  = (const float*)d_in[13];
    const float* eW2  = (const float*)d_in[14];
    const float* Wout = (const float*)d_in[15];
    float* outp = (float*)d_out;

    float* WS = (float*)d_ws;
    const size_t SZ = (size_t)8192 * 512;
    float* P0 = WS, *P1 = WS + SZ, *P2 = WS + 2 * SZ, *P3 = WS + 3 * SZ, *P4 = WS + 4 * SZ;

    // weight planes (shorts) after the 5 f32 planes
    unsigned short* SP   = (unsigned short*)(WS + 5 * SZ);
    unsigned short* sW1p = SP;                      // [3][2048][512]
    unsigned short* sW2p = SP + 3145728;            // [3][512][2048]
    unsigned short* xWq  = SP + 6291456;            // [4][512][512]
    unsigned short* xWk  = xWq + 1048576;
    unsigned short* xWv  = xWk + 1048576;
    unsigned short* xWo  = xWv + 1048576;
    unsigned short* xW1  = xWo + 1048576;           // [4][2048][512]
    unsigned short* xW2  = xW1 + 4194304;           // [4][512][2048]

    float* MBase = WS + 5 * SZ + 9437184;           // misc region
    int* IDX    = (int*)MBase;
    int* cnt    = (int*)(MBase + 8192);
    int* OFFp   = (int*)(MBase + 8224);
    int* cursor = (int*)(MBase + 8264);
    int* flat   = (int*)(MBase + 8304);
    float* M32  = MBase + 16640;                    // [4][128][512]
    float* G0   = M32 + 262144;
    float* G2   = G0 + 262144;
    float* SB   = G2 + 262144;

    // shared-phase aliases
    float* X = P4, *Qb = P0, *Kb = P1, *Vb = P2, *AO = P3, *T0 = P4, *T1 = P0, *Hb = P4;
    // expert-phase aliases
    float* Qc = P0, *Kc = P1, *Vc = P2;
    unsigned short* AOc = (unsigned short*)P3;              // [8192][512] bf16 (P3a)
    unsigned short* T0c = (unsigned short*)(P3 + 2097152);  // [8192][512] bf16 (P3b)
    unsigned short* T1c = (unsigned short*)P0;              // [8192][2048] bf16 (P0..P1)
    float* G1 = P2;                                         // [4][128][2048]
    float* OA = P3;

    const int M = 8192, D = 512, FF = 2048;
    const size_t sDD = (size_t)D * D, sDF = (size_t)D * FF;
    const float* NUL = nullptr;
    float* NULm = nullptr;

    // ---- weight prep: transpose+split once per call (~20 us) ----
    wsplit_kernel<3><<<dim3(32, 8, 1),  256, 0, stream>>>(W1, NUL, NUL, NUL, sW1p, 0, 0, 0, D, FF, 1, 0, 0);
    wsplit_kernel<3><<<dim3(8, 32, 1),  256, 0, stream>>>(W2, NUL, NUL, NUL, sW2p, 0, 0, 0, FF, D, 1, 0, 0);
    wsplit_kernel<1><<<dim3(8, 8, 16),  256, 0, stream>>>(eWq, eWk, eWv, eWo, xWq, xWk, xWv, xWo, D, D, 4, sDD, 262144);
    wsplit_kernel<1><<<dim3(32, 8, 4),  256, 0, stream>>>(eW1, NUL, NUL, NUL, xW1, 0, 0, 0, D, FF, 4, sDF, 1048576);
    wsplit_kernel<1><<<dim3(8, 32, 4),  256, 0, stream>>>(eW2, NUL, NUL, NUL, xW2, 0, 0, 0, FF, D, 4, sDF, 1048576);

    // ---- shared block (argmax-safe, 6-term split) ----
    gather_kernel<<<8192, 128, 0, stream>>>(tokens, emb, X);
    gemm_kernel<6, 0, 0, 3, 0, 0, 0><<<dim3(64, 4, 3), 256, 0, stream>>>(
        X, Wq, Wk, Wv, Qb, Kb, Vb, M, D, D, 0, 0, 0, nullptr, nullptr);
    attn_kernel<<<1024, 256, 0, stream>>>(Qb, Kb, Vb, AO);
    gemm_kernel<6, 0, 0, 1, 0, 0, 0><<<dim3(64, 4, 1), 256, 0, stream>>>(
        AO, Wo, NUL, NUL, T0, NULm, NULm, M, D, D, 0, 0, 0, nullptr, nullptr);
    gemm_kernel<6, 0, 0, 1, 1, 0, 0><<<dim3(64, 16, 1), 256, 0, stream>>>(
        T0, sW1p, NUL, NUL, T1, NULm, NULm, M, FF, D, 0, 0, 0, nullptr, nullptr);
    gemm_kernel<6, 0, 0, 1, 1, 0, 0><<<dim3(64, 4, 1), 256, 0, stream>>>(
        T1, sW2p, NUL, NUL, Hb, NULm, NULm, M, D, FF, 0, 0, 0, nullptr, nullptr);
    gate_kernel<<<2048, 256, 0, stream>>>(Hb, Wg, IDX);

    // ---- compaction ----
    hipMemsetAsync(cnt, 0, 32 * sizeof(int), stream);
    hipMemsetAsync(M32, 0, 4 * 128 * 512 * sizeof(float), stream);
    hipMemsetAsync(G2, 0, 262144 * sizeof(float), stream);   // meanV stage-3 accumulates
    count_kernel<<<32, 256, 0, stream>>>(IDX, cnt);
    offsets_kernel<<<1, 64, 0, stream>>>(cnt, OFFp, cursor);
    fill_kernel<<<32, 256, 0, stream>>>(IDX, cursor, flat);

    // ---- expert QKV (gather A=Hb f32, pre-split B planes, C f32 compact) ----
    gemm_kernel<1, 2, 1, 3, 1, 0, 0><<<dim3(64, 4, 12), 256, 0, stream>>>(
        Hb, xWq, xWk, xWv, Qc, Kc, Vc, M, D, D, 0, 262144, 0, OFFp, flat);
    sumv_kernel<<<256, 256, 0, stream>>>(Vc, OFFp, M32);
    attn_compact_kernel<<<4096, 256, 0, stream>>>(Qc, Kc, Vc, M32, AOc, OFFp);

    // ---- expert FFN chain (A bf16 direct, B planes, C bf16) ----
    gemm_kernel<1, 1, 1, 1, 1, 1, 1><<<dim3(64, 4, 4), 256, 0, stream>>>(
        AOc, xWo, NUL, NUL, T0c, NULm, NULm, M, D, D, 0, 262144, 0, OFFp, flat);
    gemm_kernel<1, 1, 1, 1, 1, 1, 1><<<dim3(64, 16, 4), 256, 0, stream>>>(
        T0c, xW1, NUL, NUL, T1c, NULm, NULm, M, FF, D, 0, 1048576, 0, OFFp, flat);

    // ---- meanV path: dedicated tiny-M kernels (weights read once, coalesced) ----
    meanv_gemm_kernel<<<dim3(8, 1, 4),  256, 0, stream>>>(M32, eWo, G0, 512,  512,  65536,  sDD, 65536);
    meanv_gemm_kernel<<<dim3(32, 1, 4), 256, 0, stream>>>(G0,  eW1, G1, 2048, 512,  65536,  sDF, 262144);
    meanv_gemm_kernel<<<dim3(8, 4, 4),  256, 0, stream>>>(G1,  eW2, G2, 512,  2048, 262144, sDF, 65536);

    // ---- expert W2: A=T1c bf16, scatter f32 into OA ----
    gemm_kernel<1, 1, 2, 1, 1, 1, 0><<<dim3(64, 4, 4), 256, 0, stream>>>(
        T1c, xW2, NUL, NUL, OA, NULm, NULm, M, D, FF, 0, 1048576, 0, OFFp, flat);

    sb_kernel<<<1, 256, 0, stream>>>(G2, Wout, SB);
    wout_kernel<<<2048, 256, 0, stream>>>(OA, Wout, SB, outp);
}

// Round 4
// 1384.120 us; speedup vs baseline: 1.6405x; 1.0908x over previous
//
#include <hip/hip_runtime.h>
#include <stdint.h>
#include <stddef.h>

// ---------- types ----------
typedef __bf16 bf16_8 __attribute__((ext_vector_type(8)));
typedef float  f32x4  __attribute__((ext_vector_type(4)));

__device__ __forceinline__ unsigned short f2bf(float f) {
    unsigned u = __float_as_uint(f);
    unsigned r = (u + 0x7fffu + ((u >> 16) & 1u)) >> 16;   // RTN-even
    return (unsigned short)r;
}
__device__ __forceinline__ float bf2f(unsigned short s) {
    return __uint_as_float(((unsigned)s) << 16);
}
__device__ __forceinline__ void split3(float v, unsigned short& h, unsigned short& l, unsigned short& l2) {
    h = f2bf(v);
    float r1 = v - bf2f(h);
    l = f2bf(r1);
    l2 = f2bf(r1 - bf2f(l));
}
__device__ __forceinline__ void split2(float v, unsigned short& h, unsigned short& l) {
    h = f2bf(v);
    l = f2bf(v - bf2f(h));
}

// ---------- weight transpose+split: src [K][N] f32 -> dst planes [P][N][K] bf16 ----------
template<int P>
__global__ __launch_bounds__(256)
void wsplit_kernel(const float* __restrict__ s0, const float* __restrict__ s1,
                   const float* __restrict__ s2, const float* __restrict__ s3,
                   unsigned short* __restrict__ d0, unsigned short* __restrict__ d1,
                   unsigned short* __restrict__ d2, unsigned short* __restrict__ d3,
                   int K, int N, int nper, size_t sstride, size_t dstride)
{
    const int z = blockIdx.z;
    const int arr = z / nper, e = z - arr * nper;
    const float* src = (arr == 0 ? s0 : arr == 1 ? s1 : arr == 2 ? s2 : s3) + (size_t)e * sstride;
    unsigned short* dst = (arr == 0 ? d0 : arr == 1 ? d1 : arr == 2 ? d2 : d3) + (size_t)e * dstride;
    const size_t NK = (size_t)N * K;
    __shared__ float T[64][65];
    const int n0 = blockIdx.x * 64, k0 = blockIdx.y * 64;
    const int tid = threadIdx.x;
#pragma unroll
    for (int i = 0; i < 16; ++i) {
        int idx = tid + (i << 8);
        int kk = idx >> 6, nn = idx & 63;
        T[kk][nn] = src[(size_t)(k0 + kk) * N + n0 + nn];
    }
    __syncthreads();
#pragma unroll
    for (int i = 0; i < 4; ++i) {
        int idx = (tid + (i << 8)) << 2;
        int nn = idx >> 6, kk = idx & 63;
        ushort4 hv, lv, l2v;
        unsigned short* hp = (unsigned short*)&hv;
        unsigned short* lp = (unsigned short*)&lv;
        unsigned short* l2p = (unsigned short*)&l2v;
#pragma unroll
        for (int j = 0; j < 4; ++j) {
            float v = T[kk + j][nn];
            unsigned short h = f2bf(v);
            hp[j] = h;
            if (P == 3) {
                float r1 = v - bf2f(h);
                unsigned short l = f2bf(r1);
                lp[j] = l;
                l2p[j] = f2bf(r1 - bf2f(l));
            }
        }
        unsigned short* dp = dst + (size_t)(n0 + nn) * K + k0 + kk;
        *(ushort4*)dp = hv;
        if (P == 3) {
            *(ushort4*)(dp + NK) = lv;
            *(ushort4*)(dp + 2 * NK) = l2v;
        }
    }
}

// ---------- GEMM: C = A * B via bf16 MFMA, 128x128 tile, BK=32, expert-batched in z ----------
// TERMS=6: 3-term split both sides (fp32-grade). TERMS=1: plain bf16.
// AMODE: 0 direct (+e*astride); 1 compact base+row; 2 gather flat[base+row].
// CMODE: 0 direct (+e*cstride); 1 compact masked; 2 scatter flat[base+row] masked.
// BPRE: 0 = B f32 [K][N], in-loop split+transpose; 1 = B pre-split bf16 planes [P][N][K].
// A16:  0 = A f32, in-loop split; 1 = A bf16 planes [NPL][M][K], pure copy staging
//       (plane stride passed via astride; expert calls use astride=0 / NPL=1).
// C16:  0 = C f32; 1 = C bf16.
template<int TERMS, int AMODE, int CMODE, int NW, int BPRE, int A16, int C16>
__global__ __launch_bounds__(256, 2)
void gemm_kernel(const void* __restrict__ Av,
                 const void* __restrict__ B0, const void* __restrict__ B1, const void* __restrict__ B2,
                 void* __restrict__ C0, void* __restrict__ C1, void* __restrict__ C2,
                 int M, int N, int K,
                 size_t astride, size_t bstride, size_t cstride,
                 const int* __restrict__ OFF, const int* __restrict__ flat)
{
    const int z = blockIdx.z;
    const int e = z / NW, w = z - e * NW;
    int base = 0, cnt = M;
    if (AMODE == 1 || AMODE == 2 || CMODE == 1 || CMODE == 2) {
        base = OFF[e * 8];
        cnt  = OFF[e * 8 + 8] - base;
        if ((int)blockIdx.x * 128 >= cnt) return;
    }
    const void* Bsel = (NW == 3 ? (w == 0 ? B0 : w == 1 ? B1 : B2) : B0);
    void*       Csel = (NW == 3 ? (w == 0 ? C0 : w == 1 ? C1 : C2) : C0);
    const float*          Af = (const float*)Av + (size_t)e * astride;
    const unsigned short* As = (const unsigned short*)Av;
    const float*          Bf = (const float*)Bsel + (size_t)e * bstride;
    const unsigned short* Bp = (const unsigned short*)Bsel + (size_t)e * bstride;
    float*          Cf = (float*)Csel + (size_t)e * cstride;
    unsigned short* Cs = (unsigned short*)Csel + (size_t)e * cstride;
    const size_t NKb = (size_t)N * K;

    constexpr int NPL = (TERMS == 6) ? 3 : 1;
    __shared__ unsigned short Asm[NPL][128 * 40];   // padded stride 40
    __shared__ unsigned short Bsm[NPL][128 * 40];   // Bsm[n][k]

    const int tid   = threadIdx.x;
    const int lane  = tid & 63;
    const int wid   = tid >> 6;
    const int wm    = wid & 1, wn = wid >> 1;
    const int mlane = lane & 15, quad = lane >> 4;
    const int row0  = blockIdx.x * 128;
    const int col0  = blockIdx.y * 128;

    f32x4 acc[4][4];
#pragma unroll
    for (int i = 0; i < 4; ++i)
#pragma unroll
        for (int j = 0; j < 4; ++j)
#pragma unroll
            for (int r = 0; r < 4; ++r) acc[i][j][r] = 0.f;

    for (int k0 = 0; k0 < K; k0 += 32) {
        // ---- stage A ----
        if (A16 == 0) {
#pragma unroll
            for (int i = 0; i < 4; ++i) {
                int idx = tid + (i << 8);
                int r = idx >> 3;
                int c = (idx & 7) << 2;
                int lr = row0 + r;
                if (AMODE != 0) lr = min(lr, cnt - 1);
                size_t arow = (AMODE == 2) ? (size_t)flat[base + lr]
                            : (AMODE == 1) ? (size_t)(base + lr) : (size_t)lr;
                const float4 a = *(const float4*)(Af + arow * K + k0 + c);
                float av[4] = {a.x, a.y, a.z, a.w};
                ushort4 hv, lv, l2v;
                unsigned short* hp  = (unsigned short*)&hv;
                unsigned short* lp  = (unsigned short*)&lv;
                unsigned short* l2p = (unsigned short*)&l2v;
#pragma unroll
                for (int j = 0; j < 4; ++j) {
                    unsigned short h = f2bf(av[j]);
                    hp[j] = h;
                    if (TERMS == 6) {
                        float r1 = av[j] - bf2f(h);
                        unsigned short l = f2bf(r1);
                        lp[j]  = l;
                        l2p[j] = f2bf(r1 - bf2f(l));
                    }
                }
                *(ushort4*)&Asm[0][r * 40 + c] = hv;
                if (TERMS == 6) {
                    *(ushort4*)&Asm[1][r * 40 + c] = lv;
                    *(ushort4*)&Asm[2][r * 40 + c] = l2v;
                }
            }
        } else {
#pragma unroll
            for (int p = 0; p < NPL; ++p)
#pragma unroll
                for (int j = 0; j < 2; ++j) {
                    int c = tid * 2 + j;                 // 512 chunks of 8 shorts
                    int r = c >> 2, q8 = (c & 3) << 3;
                    int lr = row0 + r;
                    if (AMODE != 0) lr = min(lr, cnt - 1);
                    size_t arow = (AMODE == 2) ? (size_t)flat[base + lr]
                                : (AMODE == 1) ? (size_t)(base + lr) : (size_t)lr;
                    *(uint4*)&Asm[p][r * 40 + q8] =
                        *(const uint4*)(As + (size_t)p * astride + arow * K + k0 + q8);
                }
        }
        // ---- stage B ----
        if (BPRE == 0) {
#pragma unroll
            for (int i = 0; i < 2; ++i) {
                int idx = tid + (i << 8);
                int kk = idx >> 4;
                int n8 = (idx & 15) << 3;
                const float* bp = Bf + (size_t)(k0 + kk) * N + col0 + n8;
                const float4 b0 = *(const float4*)bp;
                const float4 b1 = *(const float4*)(bp + 4);
                float bv[8] = {b0.x, b0.y, b0.z, b0.w, b1.x, b1.y, b1.z, b1.w};
#pragma unroll
                for (int j = 0; j < 8; ++j) {
                    unsigned short h = f2bf(bv[j]);
                    Bsm[0][(n8 + j) * 40 + kk] = h;
                    if (TERMS == 6) {
                        float r1 = bv[j] - bf2f(h);
                        unsigned short l = f2bf(r1);
                        Bsm[1][(n8 + j) * 40 + kk] = l;
                        Bsm[2][(n8 + j) * 40 + kk] = f2bf(r1 - bf2f(l));
                    }
                }
            }
        } else {
#pragma unroll
            for (int p = 0; p < NPL; ++p)
#pragma unroll
                for (int j = 0; j < 2; ++j) {
                    int c = tid * 2 + j;
                    int r = c >> 2, q8 = (c & 3) << 3;
                    *(uint4*)&Bsm[p][r * 40 + q8] =
                        *(const uint4*)(Bp + (size_t)p * NKb + (size_t)(col0 + r) * K + k0 + q8);
                }
        }
        __syncthreads();

        bf16_8 fa[3][4], fb[3][4];
#pragma unroll
        for (int t = 0; t < 4; ++t) {
            int ar = (wm * 64 + t * 16 + mlane) * 40 + quad * 8;
            int br = (wn * 64 + t * 16 + mlane) * 40 + quad * 8;
            fa[0][t] = *(const bf16_8*)&Asm[0][ar];
            fb[0][t] = *(const bf16_8*)&Bsm[0][br];
            if (TERMS == 6) {
                fa[1][t] = *(const bf16_8*)&Asm[1][ar];
                fa[2][t] = *(const bf16_8*)&Asm[2][ar];
                fb[1][t] = *(const bf16_8*)&Bsm[1][br];
                fb[2][t] = *(const bf16_8*)&Bsm[2][br];
            }
        }
        const int ta[6] = {0, 0, 1, 0, 1, 2};
        const int tb[6] = {0, 1, 0, 2, 1, 0};
#pragma unroll
        for (int s = 0; s < TERMS; ++s)
#pragma unroll
            for (int mt = 0; mt < 4; ++mt)
#pragma unroll
                for (int nt = 0; nt < 4; ++nt)
                    acc[mt][nt] = __builtin_amdgcn_mfma_f32_16x16x32_bf16(
                        fa[ta[s]][mt], fb[tb[s]][nt], acc[mt][nt], 0, 0, 0);
        __syncthreads();
    }

    // ---- epilogue: C/D layout col=lane&15, row=quad*4+reg ----
#pragma unroll
    for (int mt = 0; mt < 4; ++mt)
#pragma unroll
        for (int nt = 0; nt < 4; ++nt) {
            int c = col0 + wn * 64 + nt * 16 + mlane;
#pragma unroll
            for (int j = 0; j < 4; ++j) {
                int lr = row0 + wm * 64 + mt * 16 + quad * 4 + j;
                if ((CMODE == 1 || CMODE == 2) && lr >= cnt) continue;
                size_t crow = (CMODE == 2) ? (size_t)flat[base + lr]
                            : (CMODE == 1) ? (size_t)(base + lr) : (size_t)lr;
                if (C16) Cs[crow * N + c] = f2bf(acc[mt][nt][j]);
                else     Cf[crow * N + c] = acc[mt][nt][j];
            }
        }
}

// ---------- meanV FFN chain: out[e][b][n] (+)= sum_k in[e][b][k]*W[e][k][n], b<8 ----------
__global__ __launch_bounds__(256)
void meanv_gemm_kernel(const float* __restrict__ in, const float* __restrict__ W,
                       float* __restrict__ out, int N, int K,
                       size_t instride, size_t wstride, size_t outstride)
{
    const int e  = blockIdx.z;
    const int nl = threadIdx.x & 63;
    const int kg = threadIdx.x >> 6;
    const int n  = blockIdx.x * 64 + nl;
    const int k0 = blockIdx.y * 512;

    const float* inp = in + (size_t)e * instride + k0;
    const float* wp  = W + (size_t)e * wstride + (size_t)(k0 + kg * 128) * N + n;

    __shared__ float mv[8][512];
    for (int i = threadIdx.x; i < 4096; i += 256) {
        int b = i >> 9, k = i & 511;
        mv[b][k] = inp[(size_t)b * K + k];
    }
    __syncthreads();

    float acc[8] = {0.f, 0.f, 0.f, 0.f, 0.f, 0.f, 0.f, 0.f};
#pragma unroll 8
    for (int k = 0; k < 128; ++k) {
        float wv = wp[(size_t)k * N];
        const float* mk = &mv[0][kg * 128 + k];
#pragma unroll
        for (int b = 0; b < 8; ++b) acc[b] += mk[b * 512] * wv;
    }

    __shared__ float red[4][8][64];
#pragma unroll
    for (int b = 0; b < 8; ++b) red[kg][b][nl] = acc[b];
    __syncthreads();
    if (kg == 0) {
        float* op = out + (size_t)e * outstride + n;
#pragma unroll
        for (int b = 0; b < 8; ++b) {
            float s = red[0][b][nl] + red[1][b][nl] + red[2][b][nl] + red[3][b][nl];
            if (gridDim.y == 1) op[(size_t)b * N] = s;
            else                atomicAdd(&op[(size_t)b * N], s);
        }
    }
}

// ---------- MFMA split-bf16 flash attention (shared block), fp32-grade ----------
__global__ __launch_bounds__(256, 2)
void attn_kernel(const float* __restrict__ Q, const float* __restrict__ Km,
                 const float* __restrict__ V, float* __restrict__ O)
{
    __shared__ __align__(16) unsigned short Ks[3][2][32][40];  // [plane][dchunk][key][dmod32+pad]
    __shared__ __align__(16) unsigned short Vt[3][64][40];     // [plane][d][key+pad]
    __shared__ __align__(16) unsigned short U[15360];          // Qs [3][2][64][40] / P [4][3][16][40]

    const int tid = threadIdx.x;
    const int lane = tid & 63;
    const int w = tid >> 6;
    const int mlane = lane & 15, quad = lane >> 4;

    const int qt = blockIdx.x & 15;
    const int h  = (blockIdx.x >> 4) & 7;
    const int b  = blockIdx.x >> 7;
    const size_t rowbase = (size_t)b * 1024;
    const int colbase = h * 64;

    // ---- stage Q tile (64 q x 64 d) as 3 bf16 planes ----
#pragma unroll
    for (int i = 0; i < 4; ++i) {
        int idx = tid + (i << 8);
        int r = idx >> 4, c4 = (idx & 15) << 2;
        const float4 a = *(const float4*)(Q + (rowbase + qt * 64 + r) * 512 + colbase + c4);
        float av[4] = {a.x, a.y, a.z, a.w};
        ushort4 hv, lv, l2v;
        unsigned short* hp  = (unsigned short*)&hv;
        unsigned short* lp  = (unsigned short*)&lv;
        unsigned short* l2p = (unsigned short*)&l2v;
#pragma unroll
        for (int j = 0; j < 4; ++j) split3(av[j], hp[j], lp[j], l2p[j]);
        int ch = c4 >> 5, cm = c4 & 31;
        *(ushort4*)&U[(((0 * 2 + ch) * 64) + r) * 40 + cm] = hv;
        *(ushort4*)&U[(((1 * 2 + ch) * 64) + r) * 40 + cm] = lv;
        *(ushort4*)&U[(((2 * 2 + ch) * 64) + r) * 40 + cm] = l2v;
    }
    __syncthreads();

    // Q B-fragments: col=q=w*16+mlane, k=d=c*32+quad*8+j  (persist in regs)
    bf16_8 fq[3][2];
#pragma unroll
    for (int p = 0; p < 3; ++p)
#pragma unroll
        for (int c = 0; c < 2; ++c)
            fq[p][c] = *(const bf16_8*)&U[(((p * 2 + c) * 64) + (w * 16 + mlane)) * 40 + quad * 8];
    __syncthreads();   // all waves done reading Qs before P region reuses U

    f32x4 oacc[4];     // O^T frags: d = mm*16+quad*4+j, q = mlane
#pragma unroll
    for (int i = 0; i < 4; ++i)
#pragma unroll
        for (int j = 0; j < 4; ++j) oacc[i][j] = 0.f;
    float m_run = -1e30f, l_run = 0.f;

    const int ta[6] = {0, 0, 1, 0, 1, 2};
    const int tb[6] = {0, 1, 0, 2, 1, 0};

    for (int tt = 0; tt < 32; ++tt) {
        __syncthreads();
        // ---- stage K tile (32 keys x 64 d), natural layout ----
#pragma unroll
        for (int i = 0; i < 2; ++i) {
            int idx = tid + (i << 8);
            int r = idx >> 4, c4 = (idx & 15) << 2;
            const float4 a = *(const float4*)(Km + (rowbase + tt * 32 + r) * 512 + colbase + c4);
            float av[4] = {a.x, a.y, a.z, a.w};
            ushort4 hv, lv, l2v;
            unsigned short* hp  = (unsigned short*)&hv;
            unsigned short* lp  = (unsigned short*)&lv;
            unsigned short* l2p = (unsigned short*)&l2v;
#pragma unroll
            for (int j = 0; j < 4; ++j) split3(av[j], hp[j], lp[j], l2p[j]);
            int ch = c4 >> 5, cm = c4 & 31;
            *(ushort4*)&Ks[0][ch][r][cm] = hv;
            *(ushort4*)&Ks[1][ch][r][cm] = lv;
            *(ushort4*)&Ks[2][ch][r][cm] = l2v;
        }
        // ---- stage V tile transposed: Vt[d][key] (coalesced dword loads) ----
#pragma unroll
        for (int i = 0; i < 2; ++i) {
            int idx = tid + (i << 8);
            int d = idx & 63, k4 = (idx >> 6) << 2;
            const float* vp = V + (rowbase + tt * 32 + k4) * 512 + colbase + d;
            float vv[4] = {vp[0], vp[512], vp[1024], vp[1536]};
            ushort4 hv, lv, l2v;
            unsigned short* hp  = (unsigned short*)&hv;
            unsigned short* lp  = (unsigned short*)&lv;
            unsigned short* l2p = (unsigned short*)&l2v;
#pragma unroll
            for (int j = 0; j < 4; ++j) split3(vv[j], hp[j], lp[j], l2p[j]);
            *(ushort4*)&Vt[0][d][k4] = hv;
            *(ushort4*)&Vt[1][d][k4] = lv;
            *(ushort4*)&Vt[2][d][k4] = l2v;
        }
        __syncthreads();

        // ---- S^T = K·Q^T, 6-term ----
        f32x4 sacc[2];
#pragma unroll
        for (int mm = 0; mm < 2; ++mm)
#pragma unroll
            for (int j = 0; j < 4; ++j) sacc[mm][j] = 0.f;
        bf16_8 fk[3][2][2];
#pragma unroll
        for (int p = 0; p < 3; ++p)
#pragma unroll
            for (int c = 0; c < 2; ++c)
#pragma unroll
                for (int mm = 0; mm < 2; ++mm)
                    fk[p][c][mm] = *(const bf16_8*)&Ks[p][c][mm * 16 + mlane][quad * 8];
#pragma unroll
        for (int s = 0; s < 6; ++s)
#pragma unroll
            for (int c = 0; c < 2; ++c)
#pragma unroll
                for (int mm = 0; mm < 2; ++mm)
                    sacc[mm] = __builtin_amdgcn_mfma_f32_16x16x32_bf16(
                        fk[ta[s]][c][mm], fq[tb[s]][c], sacc[mm], 0, 0, 0);

        // ---- online softmax: lane owns q=mlane, keys mm*16+quad*4+j ----
        float sv[2][4];
#pragma unroll
        for (int mm = 0; mm < 2; ++mm)
#pragma unroll
            for (int j = 0; j < 4; ++j) sv[mm][j] = sacc[mm][j] * 0.125f;
        float tmax = sv[0][0];
#pragma unroll
        for (int mm = 0; mm < 2; ++mm)
#pragma unroll
            for (int j = 0; j < 4; ++j) tmax = fmaxf(tmax, sv[mm][j]);
        tmax = fmaxf(tmax, __shfl_xor(tmax, 16));
        tmax = fmaxf(tmax, __shfl_xor(tmax, 32));
        float mnew = fmaxf(m_run, tmax);
        float alpha = __expf(m_run - mnew);
        float lsum = 0.f;
#pragma unroll
        for (int mm = 0; mm < 2; ++mm)
#pragma unroll
            for (int j = 0; j < 4; ++j) {
                float p = __expf(sv[mm][j] - mnew);
                sv[mm][j] = p;
                lsum += p;
            }
        lsum += __shfl_xor(lsum, 16);
        lsum += __shfl_xor(lsum, 32);
        l_run = l_run * alpha + lsum;
        m_run = mnew;
#pragma unroll
        for (int mm = 0; mm < 4; ++mm)
#pragma unroll
            for (int j = 0; j < 4; ++j) oacc[mm][j] *= alpha;

        // ---- split P to 3 bf16 planes, per-wave LDS round-trip ----
#pragma unroll
        for (int mm = 0; mm < 2; ++mm) {
            ushort4 hv, lv, l2v;
            unsigned short* hp  = (unsigned short*)&hv;
            unsigned short* lp  = (unsigned short*)&lv;
            unsigned short* l2p = (unsigned short*)&l2v;
#pragma unroll
            for (int j = 0; j < 4; ++j) split3(sv[mm][j], hp[j], lp[j], l2p[j]);
            int col = mm * 16 + quad * 4;
            *(ushort4*)&U[((w * 3 + 0) * 16 + mlane) * 40 + col] = hv;
            *(ushort4*)&U[((w * 3 + 1) * 16 + mlane) * 40 + col] = lv;
            *(ushort4*)&U[((w * 3 + 2) * 16 + mlane) * 40 + col] = l2v;
        }

        // ---- O^T += V^T·P^T, 6-term ----
        bf16_8 fp[3], fv[3][4];
#pragma unroll
        for (int p = 0; p < 3; ++p) {
            fp[p] = *(const bf16_8*)&U[((w * 3 + p) * 16 + mlane) * 40 + quad * 8];
#pragma unroll
            for (int mm = 0; mm < 4; ++mm)
                fv[p][mm] = *(const bf16_8*)&Vt[p][mm * 16 + mlane][quad * 8];
        }
#pragma unroll
        for (int s = 0; s < 6; ++s)
#pragma unroll
            for (int mm = 0; mm < 4; ++mm)
                oacc[mm] = __builtin_amdgcn_mfma_f32_16x16x32_bf16(
                    fv[ta[s]][mm], fp[tb[s]], oacc[mm], 0, 0, 0);
    }

    // ---- epilogue: lane holds q=mlane, d=mm*16+quad*4+j ----
    const float inv = 1.f / l_run;
    const size_t orow = (rowbase + qt * 64 + w * 16 + mlane) * 512 + colbase;
#pragma unroll
    for (int mm = 0; mm < 4; ++mm)
#pragma unroll
        for (int j = 0; j < 4; ++j)
            O[orow + mm * 16 + quad * 4 + j] = oacc[mm][j] * inv;
}

// ---------- MFMA split-bf16 compacted expert attention (3-term, 2-plane) ----------
__global__ __launch_bounds__(256, 3)
void attn_compact_kernel(const float* __restrict__ Qc, const float* __restrict__ Kc,
                         const float* __restrict__ Vc, const float* __restrict__ meanV,
                         unsigned short* __restrict__ AOc, const int* __restrict__ OFF)
{
    const int qt = blockIdx.x & 15;
    const int h  = (blockIdx.x >> 4) & 7;
    const int e  = (blockIdx.x >> 7) & 3;
    const int b  = blockIdx.x >> 9;
    const int base = OFF[e * 8 + b];
    const int c    = OFF[e * 8 + b + 1] - base;
    if (qt * 64 >= c) return;
    const int nq = min(64, c - qt * 64);

    __shared__ __align__(16) unsigned short Ks[2][2][32][40];  // [plane][dchunk][key][dmod32+pad]
    __shared__ __align__(16) unsigned short Vt[2][64][40];     // [plane][d][key+pad]
    __shared__ __align__(16) unsigned short U[10240];          // Qs [2][2][64][40] / P [4][2][16][40]

    const int tid = threadIdx.x;
    const int lane = tid & 63;
    const int w = tid >> 6;
    const int mlane = lane & 15, quad = lane >> 4;
    const int colbase = h * 64;
    const int cmax = c - 1;

    // ---- stage Q tile (64 q x 64 d, row-clamped) as 2 bf16 planes ----
#pragma unroll
    for (int i = 0; i < 4; ++i) {
        int idx = tid + (i << 8);
        int r = idx >> 4, c4 = (idx & 15) << 2;
        const size_t g = (size_t)(base + min(qt * 64 + r, cmax)) * 512 + colbase + c4;
        const float4 a = *(const float4*)(Qc + g);
        float av[4] = {a.x, a.y, a.z, a.w};
        ushort4 hv, lv;
        unsigned short* hp = (unsigned short*)&hv;
        unsigned short* lp = (unsigned short*)&lv;
#pragma unroll
        for (int j = 0; j < 4; ++j) split2(av[j], hp[j], lp[j]);
        int ch = c4 >> 5, cm = c4 & 31;
        *(ushort4*)&U[(((0 * 2 + ch) * 64) + r) * 40 + cm] = hv;
        *(ushort4*)&U[(((1 * 2 + ch) * 64) + r) * 40 + cm] = lv;
    }
    __syncthreads();

    // Q B-fragments: col=q=w*16+mlane, k=d=c*32+quad*8+j (persist in regs)
    bf16_8 fq[2][2];
#pragma unroll
    for (int p = 0; p < 2; ++p)
#pragma unroll
        for (int cc = 0; cc < 2; ++cc)
            fq[p][cc] = *(const bf16_8*)&U[(((p * 2 + cc) * 64) + (w * 16 + mlane)) * 40 + quad * 8];
    __syncthreads();   // all waves done reading Qs before P region reuses U

    f32x4 oacc[4];     // O^T frags: d = mm*16+quad*4+j, q = mlane
#pragma unroll
    for (int i = 0; i < 4; ++i)
#pragma unroll
        for (int j = 0; j < 4; ++j) oacc[i][j] = 0.f;
    float m_run = -1e30f, l_run = 0.f;

    const int ta3[3] = {0, 0, 1};
    const int tb3[3] = {0, 1, 0};

    for (int kt = 0; kt * 32 < c; ++kt) {
        __syncthreads();
        // ---- stage K tile (32 keys x 64 d, row-clamped), 2 planes ----
#pragma unroll
        for (int i = 0; i < 2; ++i) {
            int idx = tid + (i << 8);
            int r = idx >> 4, c4 = (idx & 15) << 2;
            const size_t g = (size_t)(base + min(kt * 32 + r, cmax)) * 512 + colbase + c4;
            const float4 a = *(const float4*)(Kc + g);
            float av[4] = {a.x, a.y, a.z, a.w};
            ushort4 hv, lv;
            unsigned short* hp = (unsigned short*)&hv;
            unsigned short* lp = (unsigned short*)&lv;
#pragma unroll
            for (int j = 0; j < 4; ++j) split2(av[j], hp[j], lp[j]);
            int ch = c4 >> 5, cm = c4 & 31;
            *(ushort4*)&Ks[0][ch][r][cm] = hv;
            *(ushort4*)&Ks[1][ch][r][cm] = lv;
        }
        // ---- stage V tile transposed: Vt[d][key] (row-clamped coalesced loads) ----
#pragma unroll
        for (int i = 0; i < 2; ++i) {
            int idx = tid + (i << 8);
            int d = idx & 63, k4 = (idx >> 6) << 2;
            float vv[4];
#pragma unroll
            for (int j = 0; j < 4; ++j)
                vv[j] = Vc[(size_t)(base + min(kt * 32 + k4 + j, cmax)) * 512 + colbase + d];
            ushort4 hv, lv;
            unsigned short* hp = (unsigned short*)&hv;
            unsigned short* lp = (unsigned short*)&lv;
#pragma unroll
            for (int j = 0; j < 4; ++j) split2(vv[j], hp[j], lp[j]);
            *(ushort4*)&Vt[0][d][k4] = hv;
            *(ushort4*)&Vt[1][d][k4] = lv;
        }
        __syncthreads();

        // ---- S^T = K·Q^T, 3-term ----
        f32x4 sacc[2];
#pragma unroll
        for (int mm = 0; mm < 2; ++mm)
#pragma unroll
            for (int j = 0; j < 4; ++j) sacc[mm][j] = 0.f;
        bf16_8 fk[2][2][2];
#pragma unroll
        for (int p = 0; p < 2; ++p)
#pragma unroll
            for (int cc = 0; cc < 2; ++cc)
#pragma unroll
                for (int mm = 0; mm < 2; ++mm)
                    fk[p][cc][mm] = *(const bf16_8*)&Ks[p][cc][mm * 16 + mlane][quad * 8];
#pragma unroll
        for (int s = 0; s < 3; ++s)
#pragma unroll
            for (int cc = 0; cc < 2; ++cc)
#pragma unroll
                for (int mm = 0; mm < 2; ++mm)
                    sacc[mm] = __builtin_amdgcn_mfma_f32_16x16x32_bf16(
                        fk[ta3[s]][cc][mm], fq[tb3[s]][cc], sacc[mm], 0, 0, 0);

        // ---- online softmax with key masking: key = kt*32 + mm*16 + quad*4 + j ----
        float sv[2][4];
#pragma unroll
        for (int mm = 0; mm < 2; ++mm)
#pragma unroll
            for (int j = 0; j < 4; ++j) {
                int kg = kt * 32 + mm * 16 + quad * 4 + j;
                sv[mm][j] = (kg < c) ? sacc[mm][j] * 0.125f : -1e30f;
            }
        float tmax = sv[0][0];
#pragma unroll
        for (int mm = 0; mm < 2; ++mm)
#pragma unroll
            for (int j = 0; j < 4; ++j) tmax = fmaxf(tmax, sv[mm][j]);
        tmax = fmaxf(tmax, __shfl_xor(tmax, 16));
        tmax = fmaxf(tmax, __shfl_xor(tmax, 32));
        float mnew = fmaxf(m_run, tmax);
        float alpha = __expf(m_run - mnew);
        float lsum = 0.f;
#pragma unroll
        for (int mm = 0; mm < 2; ++mm)
#pragma unroll
            for (int j = 0; j < 4; ++j) {
                float p = __expf(sv[mm][j] - mnew);
                sv[mm][j] = p;
                lsum += p;
            }
        lsum += __shfl_xor(lsum, 16);
        lsum += __shfl_xor(lsum, 32);
        l_run = l_run * alpha + lsum;
        m_run = mnew;
#pragma unroll
        for (int mm = 0; mm < 4; ++mm)
#pragma unroll
            for (int j = 0; j < 4; ++j) oacc[mm][j] *= alpha;

        // ---- split P to 2 bf16 planes, per-wave LDS round-trip ----
#pragma unroll
        for (int mm = 0; mm < 2; ++mm) {
            ushort4 hv, lv;
            unsigned short* hp = (unsigned short*)&hv;
            unsigned short* lp = (unsigned short*)&lv;
#pragma unroll
            for (int j = 0; j < 4; ++j) split2(sv[mm][j], hp[j], lp[j]);
            int col = mm * 16 + quad * 4;
            *(ushort4*)&U[((w * 2 + 0) * 16 + mlane) * 40 + col] = hv;
            *(ushort4*)&U[((w * 2 + 1) * 16 + mlane) * 40 + col] = lv;
        }

        // ---- O^T += V^T·P^T, 3-term ----
        bf16_8 fp[2], fv[2][4];
#pragma unroll
        for (int p = 0; p < 2; ++p) {
            fp[p] = *(const bf16_8*)&U[((w * 2 + p) * 16 + mlane) * 40 + quad * 8];
#pragma unroll
            for (int mm = 0; mm < 4; ++mm)
                fv[p][mm] = *(const bf16_8*)&Vt[p][mm * 16 + mlane][quad * 8];
        }
#pragma unroll
        for (int s = 0; s < 3; ++s)
#pragma unroll
            for (int mm = 0; mm < 4; ++mm)
                oacc[mm] = __builtin_amdgcn_mfma_f32_16x16x32_bf16(
                    fv[ta3[s]][mm], fp[tb3[s]], oacc[mm], 0, 0, 0);
    }

    // ---- zero-key correction: (1024-c) keys with logit 0, value 0 ----
    float mfin = (c < 1024) ? fmaxf(m_run, 0.f) : m_run;
    float alphaf = __expf(m_run - mfin);
    l_run = l_run * alphaf + (float)(1024 - c) * __expf(-mfin);
#pragma unroll
    for (int mm = 0; mm < 4; ++mm)
#pragma unroll
        for (int j = 0; j < 4; ++j) oacc[mm][j] *= alphaf;

    // ---- epilogue: lane holds q=w*16+mlane, d=mm*16+quad*4+j; out = attn - meanV, bf16 ----
    const int qi = w * 16 + mlane;
    if (qi < nq) {
        const float inv = 1.f / l_run;
        const size_t orow = (size_t)(base + qt * 64 + qi) * 512 + colbase;
        const float* mv = meanV + e * 65536 + b * 512 + colbase;
#pragma unroll
        for (int mm = 0; mm < 4; ++mm) {
            int d0 = mm * 16 + quad * 4;
            ushort4 o;
            o.x = f2bf(oacc[mm][0] * inv - mv[d0 + 0]);
            o.y = f2bf(oacc[mm][1] * inv - mv[d0 + 1]);
            o.z = f2bf(oacc[mm][2] * inv - mv[d0 + 2]);
            o.w = f2bf(oacc[mm][3] * inv - mv[d0 + 3]);
            *(ushort4*)&AOc[orow + d0] = o;
        }
    }
}

// ---------- meanV per (b,e,h): M32[e][b][h*64+d] = sum(Vc rows)/1024 ----------
__global__ void sumv_kernel(const float* __restrict__ Vc, const int* __restrict__ OFF,
                            float* __restrict__ M32)
{
    const int h = blockIdx.x & 7, e = (blockIdx.x >> 3) & 3, b = blockIdx.x >> 5;
    const int base = OFF[e * 8 + b], c = OFF[e * 8 + b + 1] - base;
    const int tid = threadIdx.x;
    const int d = tid & 63, g = tid >> 6;
    float s = 0.f;
    for (int r = g; r < c; r += 4) s += Vc[(size_t)(base + r) * 512 + h * 64 + d];
    __shared__ float red[256];
    red[tid] = s;
    __syncthreads();
    if (g == 0)
        M32[e * 65536 + b * 512 + h * 64 + d] =
            (red[d] + red[64 + d] + red[128 + d] + red[192 + d]) * (1.f / 1024.f);
}

// ---------- embedding gather -> 3-plane bf16 split X (plane stride 8192*512) ----------
__global__ void gather_kernel(const int* __restrict__ tokens,
                              const float* __restrict__ emb,
                              unsigned short* __restrict__ Xp)
{
    const int t = blockIdx.x;
    const int tok = tokens[t];
    const int d4 = threadIdx.x * 4;
    const float4 a = *(const float4*)(emb + (size_t)tok * 512 + d4);
    float av[4] = {a.x, a.y, a.z, a.w};
    ushort4 hv, lv, l2v;
    unsigned short* hp  = (unsigned short*)&hv;
    unsigned short* lp  = (unsigned short*)&lv;
    unsigned short* l2p = (unsigned short*)&l2v;
#pragma unroll
    for (int j = 0; j < 4; ++j) split3(av[j], hp[j], lp[j], l2p[j]);
    const size_t o = (size_t)t * 512 + d4;
    *(ushort4*)&Xp[o]           = hv;
    *(ushort4*)&Xp[o + 4194304] = lv;
    *(ushort4*)&Xp[o + 8388608] = l2v;
}

// ---------- gate + argmax ----------
__global__ __launch_bounds__(256)
void gate_kernel(const float* __restrict__ H, const float* __restrict__ Wg,
                 int* __restrict__ idx)
{
    const int t = blockIdx.x * 4 + (threadIdx.x >> 6);
    const int lane = threadIdx.x & 63;
    float a0 = 0, a1 = 0, a2 = 0, a3 = 0;
#pragma unroll
    for (int i = 0; i < 8; ++i) {
        int d = i * 64 + lane;
        float hv = H[(size_t)t * 512 + d];
        a0 += hv * Wg[d * 4 + 0];
        a1 += hv * Wg[d * 4 + 1];
        a2 += hv * Wg[d * 4 + 2];
        a3 += hv * Wg[d * 4 + 3];
    }
#pragma unroll
    for (int off = 32; off > 0; off >>= 1) {
        a0 += __shfl_down(a0, off);
        a1 += __shfl_down(a1, off);
        a2 += __shfl_down(a2, off);
        a3 += __shfl_down(a3, off);
    }
    if (lane == 0) {
        int best = 0; float bv = a0;
        if (a1 > bv) { bv = a1; best = 1; }
        if (a2 > bv) { bv = a2; best = 2; }
        if (a3 > bv) { bv = a3; best = 3; }
        idx[t] = best;
    }
}

// ---------- compaction: count / offsets / fill ----------
__global__ void count_kernel(const int* __restrict__ idx, int* __restrict__ cnt)
{
    const int t = blockIdx.x * 256 + threadIdx.x;
    atomicAdd(&cnt[idx[t] * 8 + (t >> 10)], 1);
}
__global__ void offsets_kernel(const int* __restrict__ cnt, int* __restrict__ OFF,
                               int* __restrict__ cursor)
{
    if (threadIdx.x == 0) {
        int a = 0;
        for (int i = 0; i < 32; ++i) { OFF[i] = a; cursor[i] = a; a += cnt[i]; }
        OFF[32] = a;
    }
}
__global__ void fill_kernel(const int* __restrict__ idx, int* __restrict__ cursor,
                            int* __restrict__ flat)
{
    const int t = blockIdx.x * 256 + threadIdx.x;
    const int p = atomicAdd(&cursor[idx[t] * 8 + (t >> 10)], 1);
    flat[p] = t;
}

// ---------- SB[b] = sum_e G2[e][b][:] . Wout ----------
__global__ void sb_kernel(const float* __restrict__ G2, const float* __restrict__ Wout,
                          float* __restrict__ SB)
{
    const int tid = threadIdx.x;
    const int pair = tid >> 3, t8 = tid & 7;
    const int e = pair >> 3, b = pair & 7;
    float s = 0.f;
    for (int d = t8; d < 512; d += 8) s += G2[e * 65536 + b * 512 + d] * Wout[d];
    __shared__ float red[256];
    __shared__ float red2[32];
    red[tid] = s;
    __syncthreads();
    if (tid < 32) {
        float t = 0.f;
#pragma unroll
        for (int k = 0; k < 8; ++k) t += red[tid * 8 + k];
        red2[tid] = t;
    }
    __syncthreads();
    if (tid < 8)
        SB[tid] = red2[tid] + red2[8 + tid] + red2[16 + tid] + red2[24 + tid];
}

// ---------- head: out[t] = OA[t,:].Wout + SB[b(t)] ----------
__global__ __launch_bounds__(256)
void wout_kernel(const float* __restrict__ OUT, const float* __restrict__ Wout,
                 const float* __restrict__ SB, float* __restrict__ out)
{
    const int t = blockIdx.x * 4 + (threadIdx.x >> 6);
    const int lane = threadIdx.x & 63;
    float s = 0.f;
#pragma unroll
    for (int i = 0; i < 8; ++i) {
        int d = i * 64 + lane;
        s += OUT[(size_t)t * 512 + d] * Wout[d];
    }
#pragma unroll
    for (int off = 32; off > 0; off >>= 1) s += __shfl_down(s, off);
    if (lane == 0) out[t] = s + SB[t >> 10];
}

// ---------- launch ----------
extern "C" void kernel_launch(void* const* d_in, const int* in_sizes, int n_in,
                              void* d_out, int out_size, void* d_ws, size_t ws_size,
                              hipStream_t stream)
{
    const int*   tokens = (const int*)d_in[0];
    const float* emb  = (const float*)d_in[1];
    const float* Wq   = (const float*)d_in[2];
    const float* Wk   = (const float*)d_in[3];
    const float* Wv   = (const float*)d_in[4];
    const float* Wo   = (const float*)d_in[5];
    const float* W1   = (const float*)d_in[6];
    const float* W2   = (const float*)d_in[7];
    const float* Wg   = (const float*)d_in[8];
    const float* eWq  = (const float*)d_in[9];
    const float* eWk  = (const float*)d_in[10];
    const float* eWv  = (const float*)d_in[11];
    const float* eWo  = (const float*)d_in[12];
    const float* eW1  = (const float*)d_in[13];
    const float* eW2  = (const float*)d_in[14];
    const float* Wout = (const float*)d_in[15];
    float* outp = (float*)d_out;

    float* WS = (float*)d_ws;
    const size_t SZ = (size_t)8192 * 512;
    float* P0 = WS, *P1 = WS + SZ, *P2 = WS + 2 * SZ, *P3 = WS + 3 * SZ, *P4 = WS + 4 * SZ;

    // weight planes (shorts) after the 5 f32 planes
    unsigned short* SP   = (unsigned short*)(WS + 5 * SZ);
    unsigned short* sW1p = SP;                      // [3][2048][512]
    unsigned short* sW2p = SP + 3145728;            // [3][512][2048]
    unsigned short* xWq  = SP + 6291456;            // shared: [3][512][512] -> later expert [4][512][512]
    unsigned short* xWk  = xWq + 1048576;
    unsigned short* xWv  = xWk + 1048576;
    unsigned short* xWo  = xWv + 1048576;
    unsigned short* xW1  = xWo + 1048576;           // [4][2048][512]
    unsigned short* xW2  = xW1 + 4194304;           // [4][512][2048]

    float* MBase = WS + 5 * SZ + 9437184;           // misc region
    int* IDX    = (int*)MBase;
    int* cnt    = (int*)(MBase + 8192);
    int* OFFp   = (int*)(MBase + 8224);
    int* cursor = (int*)(MBase + 8264);
    int* flat   = (int*)(MBase + 8304);
    float* M32  = MBase + 16640;                    // [4][128][512]
    float* G0   = M32 + 262144;
    float* G2   = G0 + 262144;
    float* SB   = G2 + 262144;

    // shared-phase aliases
    float* Qb = P0, *Kb = P1, *Vb = P2, *AO = P3, *T0 = P4, *T1 = P0, *Hb = P4;
    unsigned short* Xp = (unsigned short*)P3;               // [3][8192][512] bf16 (P3 + first half of P4);
                                                            // dead before attn writes AO=P3 / AO·Wo writes T0=P4
    // expert-phase aliases
    float* Qc = P0, *Kc = P1, *Vc = P2;
    unsigned short* AOc = (unsigned short*)P3;              // [8192][512] bf16 (P3a)
    unsigned short* T0c = (unsigned short*)(P3 + 2097152);  // [8192][512] bf16 (P3b)
    unsigned short* T1c = (unsigned short*)P0;              // [8192][2048] bf16 (P0..P1)
    float* G1 = P2;                                         // [4][128][2048]
    float* OA = P3;

    const int M = 8192, D = 512, FF = 2048;
    const size_t sDD = (size_t)D * D, sDF = (size_t)D * FF;
    const float* NUL = nullptr;
    float* NULm = nullptr;

    // ---- weight prep: shared FFN + shared QKV/O (3-plane, into xW* regions) + expert FFN ----
    wsplit_kernel<3><<<dim3(32, 8, 1),  256, 0, stream>>>(W1, NUL, NUL, NUL, sW1p, 0, 0, 0, D, FF, 1, 0, 0);
    wsplit_kernel<3><<<dim3(8, 32, 1),  256, 0, stream>>>(W2, NUL, NUL, NUL, sW2p, 0, 0, 0, FF, D, 1, 0, 0);
    wsplit_kernel<3><<<dim3(8, 8, 4),   256, 0, stream>>>(Wq, Wk, Wv, Wo, xWq, xWk, xWv, xWo, D, D, 1, 0, 0);
    wsplit_kernel<1><<<dim3(32, 8, 4),  256, 0, stream>>>(eW1, NUL, NUL, NUL, xW1, 0, 0, 0, D, FF, 4, sDF, 1048576);
    wsplit_kernel<1><<<dim3(8, 32, 4),  256, 0, stream>>>(eW2, NUL, NUL, NUL, xW2, 0, 0, 0, FF, D, 4, sDF, 1048576);

    // ---- shared block (argmax-safe, 6-term split; A and B both pre-split) ----
    gather_kernel<<<8192, 128, 0, stream>>>(tokens, emb, Xp);
    gemm_kernel<6, 0, 0, 3, 1, 1, 0><<<dim3(64, 4, 3), 256, 0, stream>>>(
        Xp, xWq, xWk, xWv, Qb, Kb, Vb, M, D, D, (size_t)M * D, 0, 0, nullptr, nullptr);
    attn_kernel<<<1024, 256, 0, stream>>>(Qb, Kb, Vb, AO);
    gemm_kernel<6, 0, 0, 1, 1, 0, 0><<<dim3(64, 4, 1), 256, 0, stream>>>(
        AO, xWo, NUL, NUL, T0, NULm, NULm, M, D, D, 0, 0, 0, nullptr, nullptr);
    // shared Wq..Wo planes now dead -> repurpose xW* regions for expert QKV/O weights
    wsplit_kernel<1><<<dim3(8, 8, 16),  256, 0, stream>>>(eWq, eWk, eWv, eWo, xWq, xWk, xWv, xWo, D, D, 4, sDD, 262144);
    gemm_kernel<6, 0, 0, 1, 1, 0, 0><<<dim3(64, 16, 1), 256, 0, stream>>>(
        T0, sW1p, NUL, NUL, T1, NULm, NULm, M, FF, D, 0, 0, 0, nullptr, nullptr);
    gemm_kernel<6, 0, 0, 1, 1, 0, 0><<<dim3(64, 4, 1), 256, 0, stream>>>(
        T1, sW2p, NUL, NUL, Hb, NULm, NULm, M, D, FF, 0, 0, 0, nullptr, nullptr);
    gate_kernel<<<2048, 256, 0, stream>>>(Hb, Wg, IDX);

    // ---- compaction ----
    hipMemsetAsync(cnt, 0, 32 * sizeof(int), stream);
    hipMemsetAsync(M32, 0, 4 * 128 * 512 * sizeof(float), stream);
    hipMemsetAsync(G2, 0, 262144 * sizeof(float), stream);   // meanV stage-3 accumulates
    count_kernel<<<32, 256, 0, stream>>>(IDX, cnt);
    offsets_kernel<<<1, 64, 0, stream>>>(cnt, OFFp, cursor);
    fill_kernel<<<32, 256, 0, stream>>>(IDX, cursor, flat);

    // ---- expert QKV (gather A=Hb f32, pre-split B planes, C f32 compact) ----
    gemm_kernel<1, 2, 1, 3, 1, 0, 0><<<dim3(64, 4, 12), 256, 0, stream>>>(
        Hb, xWq, xWk, xWv, Qc, Kc, Vc, M, D, D, 0, 262144, 0, OFFp, flat);
    sumv_kernel<<<256, 256, 0, stream>>>(Vc, OFFp, M32);
    attn_compact_kernel<<<4096, 256, 0, stream>>>(Qc, Kc, Vc, M32, AOc, OFFp);

    // ---- expert FFN chain (A bf16 direct, B planes, C bf16) ----
    gemm_kernel<1, 1, 1, 1, 1, 1, 1><<<dim3(64, 4, 4), 256, 0, stream>>>(
        AOc, xWo, NUL, NUL, T0c, NULm, NULm, M, D, D, 0, 262144, 0, OFFp, flat);
    gemm_kernel<1, 1, 1, 1, 1, 1, 1><<<dim3(64, 16, 4), 256, 0, stream>>>(
        T0c, xW1, NUL, NUL, T1c, NULm, NULm, M, FF, D, 0, 1048576, 0, OFFp, flat);

    // ---- meanV path: dedicated tiny-M kernels (weights read once, coalesced) ----
    meanv_gemm_kernel<<<dim3(8, 1, 4),  256, 0, stream>>>(M32, eWo, G0, 512,  512,  65536,  sDD, 65536);
    meanv_gemm_kernel<<<dim3(32, 1, 4), 256, 0, stream>>>(G0,  eW1, G1, 2048, 512,  65536,  sDF, 262144);
    meanv_gemm_kernel<<<dim3(8, 4, 4),  256, 0, stream>>>(G1,  eW2, G2, 512,  2048, 262144, sDF, 65536);

    // ---- expert W2: A=T1c bf16, scatter f32 into OA ----
    gemm_kernel<1, 1, 2, 1, 1, 1, 0><<<dim3(64, 4, 4), 256, 0, stream>>>(
        T1c, xW2, NUL, NUL, OA, NULm, NULm, M, D, FF, 0, 1048576, 0, OFFp, flat);

    sb_kernel<<<1, 256, 0, stream>>>(G2, Wout, SB);
    wout_kernel<<<2048, 256, 0, stream>>>(OA, Wout, SB, outp);
}